// Round 5
// baseline (708.653 us; speedup 1.0000x reference)
//
#include <hip/hip_runtime.h>
#include <hip/hip_bf16.h>
#include <math.h>

#define B_ 8
#define L_ 2048
#define DM 256
#define DIP 1064
#define DI 512
#define CD 544
#define DSZ 16
#define NH 8
#define HD 64
#define Q_ 64
#define NC 32

typedef __attribute__((ext_vector_type(8))) short bf16x8;
typedef __attribute__((ext_vector_type(4))) float f32x4;

__device__ inline unsigned short f2bf(float f) {
    __hip_bfloat16 h = __float2bfloat16(f);
    return *(unsigned short*)&h;
}
__device__ inline float bf2f(unsigned short u) {
    unsigned int x = ((unsigned int)u) << 16;
    return __uint_as_float(x);
}

// ---------------- fp32 -> bf16 bulk convert ----------------
__global__ __launch_bounds__(256) void k_f2bf(const float* __restrict__ in, unsigned short* __restrict__ out, int n4) {
    int i = blockIdx.x * 256 + threadIdx.x;
    if (i >= n4) return;
    float4 v = *(const float4*)(in + (size_t)i * 4);
    ushort4 o;
    o.x = f2bf(v.x); o.y = f2bf(v.y); o.z = f2bf(v.z); o.w = f2bf(v.w);
    *(ushort4*)(out + (size_t)i * 4) = o;
}

// ---------------- embed ----------------
__global__ __launch_bounds__(256) void k_embed(const int* __restrict__ x, const float* __restrict__ mask,
                                               const float* __restrict__ emb, const float* __restrict__ pos,
                                               float* __restrict__ h, unsigned short* __restrict__ h_bf) {
    int i = blockIdx.x * 256 + threadIdx.x;
    if (i >= B_ * L_ * DM) return;
    int d = i % DM;
    int bl = i / DM;
    int l = bl % L_;
    int tok = x[bl];
    float v = (emb[tok * DM + d] + pos[l * DM + d]) * mask[bl];
    h[i] = v;
    h_bf[i] = f2bf(v);
}

// ---------------- bf16 MFMA NT GEMM (128x128 tile, BK=32, global_load_lds) ----------------
// OUTMODE 0: fp32 C.  OUTMODE 1: bf16 C + fp32 dtraw side-buffer for cols >= DI+CD.
template <int OUTMODE>
__global__ __launch_bounds__(256) void k_gemm(const unsigned short* __restrict__ A, int lda,
                                              const unsigned short* __restrict__ Bw, int ldb, int N,
                                              void* __restrict__ Cout, int ldc, int K,
                                              float* __restrict__ dtraw) {
    __shared__ unsigned short Al[2][128 * 32];
    __shared__ unsigned short Bl[2][128 * 32];
    int tid = threadIdx.x;
    int l = tid & 63;
    int w = tid >> 6, wr = w >> 1, wc = w & 1;
    int m0 = blockIdx.x * 128, n0 = blockIdx.y * 128;

    f32x4 zero = {0.f, 0.f, 0.f, 0.f};
    f32x4 acc[4][4];
#pragma unroll
    for (int i = 0; i < 4; i++)
#pragma unroll
        for (int j = 0; j < 4; j++) acc[i][j] = zero;

    int lr = l & 15, kq = l >> 4;
    int aoff = (wr * 64 + lr) * 32 + kq * 8;
    int boff = (wc * 64 + lr) * 32 + kq * 8;

    auto stage = [&](int ks, int buf) {
        int k0 = ks * 32;
#pragma unroll
        for (int q = 0; q < 2; q++) {
            int c = tid + q * 256;
            int row = c >> 2, cc = (c & 3) * 8;
            const unsigned short* ga = A + (size_t)(m0 + row) * lda + k0 + cc;
            __builtin_amdgcn_global_load_lds((const __attribute__((address_space(1))) void*)ga,
                                             (__attribute__((address_space(3))) void*)(&Al[buf][c * 8]), 16, 0, 0);
            int rowb = n0 + row;
            if (rowb > N - 1) rowb = N - 1;
            const unsigned short* gb = Bw + (size_t)rowb * ldb + k0 + cc;
            __builtin_amdgcn_global_load_lds((const __attribute__((address_space(1))) void*)gb,
                                             (__attribute__((address_space(3))) void*)(&Bl[buf][c * 8]), 16, 0, 0);
        }
    };

    stage(0, 0);
    int ksteps = K / 32;
    for (int s = 0; s < ksteps; s++) {
        int buf = s & 1;
        __syncthreads();
        if (s + 1 < ksteps) stage(s + 1, buf ^ 1);
        bf16x8 a[4], b[4];
#pragma unroll
        for (int i = 0; i < 4; i++) a[i] = *(const bf16x8*)&Al[buf][aoff + i * 512];
#pragma unroll
        for (int j = 0; j < 4; j++) b[j] = *(const bf16x8*)&Bl[buf][boff + j * 512];
#pragma unroll
        for (int i = 0; i < 4; i++)
#pragma unroll
            for (int j = 0; j < 4; j++)
                acc[i][j] = __builtin_amdgcn_mfma_f32_16x16x32_bf16(a[i], b[j], acc[i][j], 0, 0, 0);
    }

#pragma unroll
    for (int i = 0; i < 4; i++) {
        int m = m0 + wr * 64 + i * 16 + kq * 4;
#pragma unroll
        for (int j = 0; j < 4; j++) {
            int n = n0 + wc * 64 + j * 16 + lr;
            if (n < N) {
                if (OUTMODE == 0) {
                    float* C = (float*)Cout;
#pragma unroll
                    for (int r = 0; r < 4; r++)
                        C[(size_t)(m + r) * ldc + n] = acc[i][j][r];
                } else {
                    unsigned short* C = (unsigned short*)Cout;
#pragma unroll
                    for (int r = 0; r < 4; r++)
                        C[(size_t)(m + r) * ldc + n] = f2bf(acc[i][j][r]);
                    if (n >= DI + CD) {
#pragma unroll
                        for (int r = 0; r < 4; r++)
                            dtraw[(size_t)(m + r) * NH + (n - (DI + CD))] = acc[i][j][r];
                    }
                }
            }
        }
    }
}

// ---------------- fused conv+silu+dt + chunked scan stage 1 (MFMA) ----------------
__global__ __launch_bounds__(256) void k_scan1c(const unsigned short* __restrict__ zxb,
                                                const float* __restrict__ dtraw,
                                                const float* __restrict__ cw, const float* __restrict__ cb,
                                                const float* __restrict__ dtb, const float* __restrict__ Alog,
                                                const float* __restrict__ Dp,
                                                float* __restrict__ ybuf, float* __restrict__ Sg,
                                                float* __restrict__ Pg, float* __restrict__ cumLg,
                                                float* __restrict__ Cc) {
    int bh = blockIdx.x, c = blockIdx.y;
    int b = bh >> 3, h = bh & 7;
    int tid = threadIdx.x;
    int t0 = c * Q_;
    int w = tid >> 6, l = tid & 63;
    int lr = l & 15, kq = l >> 4;

    __shared__ __align__(16) unsigned short Zl[67 * 96];       // staged zx slice; aliased by Mbf/Btw later
    __shared__ __align__(16) float Xs[Q_][HD];
    __shared__ __align__(16) float Bsf[Q_][DSZ];
    __shared__ __align__(16) float Csf[Q_][DSZ];
    __shared__ __align__(16) unsigned short Xt[Q_ * 72];
    __shared__ __align__(16) unsigned short Cbf[Q_ * 32];
    __shared__ __align__(16) unsigned short Bbf[Q_ * 32];
    __shared__ float Lc[Q_], dts[Q_], coefS[Q_];
    unsigned short* Mbf = Zl;            // 64*64 shorts (after conv phase, Zl is dead)
    unsigned short* Btw = Zl + 4096;     // 16*72 shorts

    float Dval = Dp[h];

    // ---- stage Zl: rows t0-3..t0+63; cols 0..63 = X head slice, 64..95 = B|C ----
    for (int idx = tid; idx < 67 * 12; idx += 256) {
        int rr = idx / 12, seg = idx - rr * 12;
        int lg = t0 - 3 + rr;
        bf16x8 v;
        if (lg >= 0) {
            const unsigned short* src = zxb + (size_t)(b * L_ + lg) * DIP +
                                        (seg < 8 ? (DI + h * HD + seg * 8) : (1024 + (seg - 8) * 8));
            v = *(const bf16x8*)src;
        } else {
#pragma unroll
            for (int j = 0; j < 8; j++) v[j] = 0;
        }
        int col = (seg < 8) ? seg * 8 : (64 + (seg - 8) * 8);
        *(bf16x8*)&Zl[rr * 96 + col] = v;
    }
    // ---- dt / ldA / log-cumsum (wave 0, independent of Zl) ----
    if (tid < 64) {
        float raw = dtraw[(size_t)(b * L_ + t0 + tid) * NH + h] + dtb[h];
        float dtv = (raw > 20.f) ? raw : log1pf(__expf(raw));
        float v = -__expf(Alog[h]) * dtv;
#pragma unroll
        for (int off = 1; off < 64; off <<= 1) {
            float u = __shfl_up(v, off);
            if (tid >= off) v += u;
        }
        dts[tid] = dtv;
        Lc[tid] = v;
        float lend = __shfl(v, 63);
        coefS[tid] = __expf(lend - v) * dtv;
        cumLg[(size_t)(bh * NC + c) * Q_ + tid] = v;
        if (tid == 63) Pg[bh * NC + c] = __expf(v);
    }
    __syncthreads();

    // ---- depthwise conv (k=4) + bias + silu -> Xs / Bsf / Csf ----
    for (int idx = tid; idx < Q_ * 96; idx += 256) {
        int t = idx / 96, ch = idx - t * 96;
        int cc = (ch < 64) ? (h * HD + ch) : (DI + (ch - 64));
        float acc = cb[cc];
#pragma unroll
        for (int k = 0; k < 4; k++)
            acc = fmaf(bf2f(Zl[(t + k) * 96 + ch]), cw[cc * 4 + k], acc);
        float s = acc / (1.f + __expf(-acc));
        if (ch < 64) Xs[t][ch] = s;
        else if (ch < 80) Bsf[t][ch - 64] = s;
        else Csf[t][ch - 80] = s;
    }
    __syncthreads();

    // ---- build bf16 operands (Zl is dead from here; Mbf/Btw alias it) ----
    {   // Cbf / Bbf (K padded to 32, dt folded into B), kblk-swizzled by row&3
        int t = tid & 63, kb = tid >> 6;
        int swz = (kb ^ (t & 3)) * 8;
        bf16x8 cv, bv;
        float dtv = dts[t];
#pragma unroll
        for (int j = 0; j < 8; j++) {
            int k = kb * 8 + j;
            float cf = (k < DSZ) ? Csf[t][k] : 0.f;
            float bf = (k < DSZ) ? dtv * Bsf[t][k] : 0.f;
            cv[j] = (short)f2bf(cf);
            bv[j] = (short)f2bf(bf);
        }
        *(bf16x8*)&Cbf[t * 32 + swz] = cv;
        *(bf16x8*)&Bbf[t * 32 + swz] = bv;
    }
    {   // Xt[p][s] = bf16(X[s][p])
        int p = tid & 63, sb = tid >> 6;
        bf16x8 lo, hi;
#pragma unroll
        for (int j = 0; j < 8; j++) {
            lo[j] = (short)f2bf(Xs[sb * 16 + j][p]);
            hi[j] = (short)f2bf(Xs[sb * 16 + 8 + j][p]);
        }
        *(bf16x8*)&Xt[p * 72 + sb * 16] = lo;
        *(bf16x8*)&Xt[p * 72 + sb * 16 + 8] = hi;
    }
    if (tid < 128) {   // Btw[n][s] = bf16(coefS[s] * B[s][n])
        int n = tid >> 3, sb = tid & 7;
        bf16x8 v;
#pragma unroll
        for (int j = 0; j < 8; j++) {
            int s = sb * 8 + j;
            v[j] = (short)f2bf(coefS[s] * Bsf[s][n]);
        }
        *(bf16x8*)&Btw[n * 72 + sb * 8] = v;
    }
    if (h == 0) {      // compact C for scan3g (shared across heads)
        int t = tid >> 2, n0 = (tid & 3) * 4;
        *(float4*)(Cc + ((size_t)(b * L_ + t0 + t)) * DSZ + n0) = *(const float4*)&Csf[t][n0];
    }
    __syncthreads();

    f32x4 zero = {0.f, 0.f, 0.f, 0.f};

    // phase 1: CB tiles (wave w owns t-tile w), K=32 (zero-padded)
    f32x4 cbt[4];
    {
        bf16x8 af = *(const bf16x8*)&Cbf[(w * 16 + lr) * 32 + ((kq ^ (lr & 3)) * 8)];
#pragma unroll
        for (int st = 0; st < 4; st++) {
            bf16x8 bf = *(const bf16x8*)&Bbf[(st * 16 + lr) * 32 + ((kq ^ (lr & 3)) * 8)];
            cbt[st] = __builtin_amdgcn_mfma_f32_16x16x32_bf16(af, bf, zero, 0, 0, 0);
        }
    }
    // mask + decay -> Mbf
#pragma unroll
    for (int st = 0; st < 4; st++) {
#pragma unroll
        for (int r = 0; r < 4; r++) {
            int t = w * 16 + kq * 4 + r;
            int s = st * 16 + lr;
            float m = (s <= t) ? __expf(Lc[t] - Lc[s]) * cbt[st][r] : 0.f;
            Mbf[t * 64 + (((s >> 3) ^ (t & 7)) * 8) + (s & 7)] = f2bf(m);
        }
    }
    __syncthreads();

    // phase 2: Y = M * X (+ D*x), write to ybuf
    {
        float* base_y = ybuf + ((size_t)b * L_ + t0) * DI + h * HD;
        f32x4 acc[4];
#pragma unroll
        for (int pt = 0; pt < 4; pt++) acc[pt] = zero;
#pragma unroll
        for (int ks = 0; ks < 2; ks++) {
            bf16x8 af = *(const bf16x8*)&Mbf[(w * 16 + lr) * 64 + (((ks * 4 + kq) ^ (lr & 7)) * 8)];
#pragma unroll
            for (int pt = 0; pt < 4; pt++) {
                bf16x8 bf = *(const bf16x8*)&Xt[(pt * 16 + lr) * 72 + ks * 32 + kq * 8];
                acc[pt] = __builtin_amdgcn_mfma_f32_16x16x32_bf16(af, bf, acc[pt], 0, 0, 0);
            }
        }
#pragma unroll
        for (int pt = 0; pt < 4; pt++) {
#pragma unroll
            for (int r = 0; r < 4; r++) {
                int t = w * 16 + kq * 4 + r;
                int p = pt * 16 + lr;
                base_y[(size_t)t * DI + p] = acc[pt][r] + Dval * Xs[t][p];
            }
        }
    }

    // phase 3: chunk state S = X^T * (coef*B)
    {
        f32x4 sacc = zero;
#pragma unroll
        for (int ks = 0; ks < 2; ks++) {
            bf16x8 af = *(const bf16x8*)&Xt[(w * 16 + lr) * 72 + ks * 32 + kq * 8];
            bf16x8 bf = *(const bf16x8*)&Btw[lr * 72 + ks * 32 + kq * 8];
            sacc = __builtin_amdgcn_mfma_f32_16x16x32_bf16(af, bf, sacc, 0, 0, 0);
        }
#pragma unroll
        for (int r = 0; r < 4; r++) {
            int p = w * 16 + kq * 4 + r;
            Sg[((size_t)(bh * NC + c) * HD + p) * DSZ + lr] = sacc[r];
        }
    }
}

// ---------------- chunked scan stage 2 ----------------
__global__ __launch_bounds__(256) void k_scan2(const float* __restrict__ Sg, const float* __restrict__ Pg,
                                               float* __restrict__ Hg) {
    int bh = blockIdx.x;
    int tid = threadIdx.x;
    int p = tid >> 2, n0 = (tid & 3) * 4;
    float4 H = make_float4(0.f, 0.f, 0.f, 0.f);
    for (int c = 0; c < NC; c++) {
        size_t base = ((size_t)(bh * NC + c) * HD + p) * DSZ + n0;
        float P = Pg[bh * NC + c];
        float4 S = *(const float4*)(Sg + base);
        *(float4*)(Hg + base) = H;
        H.x = fmaf(P, H.x, S.x);
        H.y = fmaf(P, H.y, S.y);
        H.z = fmaf(P, H.z, S.z);
        H.w = fmaf(P, H.w, S.w);
    }
}

// ---------------- fused scan stage 3 + gated RMSNorm -> bf16 yn ----------------
// grid (B_, 128): block handles 16 rows x all 512 channels.
__global__ __launch_bounds__(256) void k_scan3g(const float* __restrict__ ybuf,
                                                const unsigned short* __restrict__ zxb,
                                                const float* __restrict__ Hg, const float* __restrict__ cumLg,
                                                const float* __restrict__ Cc, const float* __restrict__ nw,
                                                unsigned short* __restrict__ yn_bf) {
    int b = blockIdx.x, by = blockIdx.y;
    int c64 = by >> 2, tl0 = (by & 3) * 16;
    int t0 = by * 16;
    int tid = threadIdx.x;
    __shared__ float Hs[NH][HD][DSZ];   // 32 KB
    __shared__ float Ccs[16][DSZ];
    __shared__ float Lq[NH][16];

#pragma unroll
    for (int k = 0; k < 8; k++) {
        int idx = k * 256 + tid;
        int hh = idx >> 8, rem = idx & 255;
        int p = rem >> 2, n0 = (rem & 3) * 4;
        *(float4*)&Hs[hh][p][n0] =
            *(const float4*)(Hg + (((size_t)(b * NH + hh) * NC + c64) * HD + p) * DSZ + n0);
    }
    if (tid < 64) {
        int t = tid >> 2, n0 = (tid & 3) * 4;
        *(float4*)&Ccs[t][n0] = *(const float4*)(Cc + ((size_t)(b * L_ + t0 + t)) * DSZ + n0);
    }
    if (tid < 128) {
        int hh = tid >> 4, t = tid & 15;
        Lq[hh][t] = cumLg[((size_t)(b * NH + hh) * NC + c64) * Q_ + tl0 + t];
    }
    __syncthreads();

    int t = tid >> 4, q = tid & 15;
    int hh = q >> 1, p0 = (q & 1) * 32;
    size_t bl = (size_t)b * L_ + t0 + t;
    float ef = __expf(Lq[hh][t]);

    const float* yrow = ybuf + bl * DI + hh * HD + p0;
    const unsigned short* zrow = zxb + bl * DIP + hh * HD + p0;
    float yv[32];
    unsigned short zv[32];
#pragma unroll
    for (int k = 0; k < 8; k++) *(float4*)&yv[k * 4] = *(const float4*)(yrow + k * 4);
#pragma unroll
    for (int k = 0; k < 4; k++) *(bf16x8*)&zv[k * 8] = *(const bf16x8*)(zrow + k * 8);

    float yg[32];
    float ss = 0.f;
#pragma unroll
    for (int j = 0; j < 32; j++) {
        int p = p0 + j;
        float d = 0.f;
#pragma unroll
        for (int n = 0; n < DSZ; n++) d = fmaf(Ccs[t][n], Hs[hh][p][n], d);
        float y = fmaf(ef, d, yv[j]);
        float z = bf2f(zv[j]);
        float g = z / (1.f + __expf(-z));
        yg[j] = y * g;
        ss = fmaf(yg[j], yg[j], ss);
    }
    ss += __shfl_xor(ss, 1);
    ss += __shfl_xor(ss, 2);
    ss += __shfl_xor(ss, 4);
    ss += __shfl_xor(ss, 8);
    float r = rsqrtf(ss * (1.f / DI) + 1e-5f);

    const float* nwp = nw + hh * HD + p0;
    unsigned short* dst = yn_bf + bl * DI + hh * HD + p0;
#pragma unroll
    for (int k = 0; k < 4; k++) {
        bf16x8 o;
#pragma unroll
        for (int j = 0; j < 8; j++) o[j] = (short)f2bf(yg[k * 8 + j] * r * nwp[k * 8 + j]);
        *(bf16x8*)(dst + k * 8) = o;
    }
}

// ---------------- residual add + LayerNorm + mask (+ bf16 copy) ----------------
__global__ __launch_bounds__(256) void k_ln(const float* __restrict__ tmp, float* __restrict__ h,
                                            unsigned short* __restrict__ h_bf,
                                            const float* __restrict__ lnw, const float* __restrict__ lnb,
                                            const float* __restrict__ mask) {
    int bl = blockIdx.x;
    int tid = threadIdx.x;
    size_t idx = (size_t)bl * DM + tid;
    float v = tmp[idx] + h[idx];
    __shared__ float red[4];
    float s = v;
#pragma unroll
    for (int m = 1; m < 64; m <<= 1) s += __shfl_xor(s, m);
    if ((tid & 63) == 0) red[tid >> 6] = s;
    __syncthreads();
    float mu = (red[0] + red[1] + red[2] + red[3]) * (1.f / DM);
    float d = v - mu;
    float q = d * d;
    __syncthreads();
#pragma unroll
    for (int m = 1; m < 64; m <<= 1) q += __shfl_xor(q, m);
    if ((tid & 63) == 0) red[tid >> 6] = q;
    __syncthreads();
    float var = (red[0] + red[1] + red[2] + red[3]) * (1.f / DM);
    float o = (d * rsqrtf(var + 1e-5f) * lnw[tid] + lnb[tid]) * mask[bl];
    h[idx] = o;
    h_bf[idx] = f2bf(o);
}

// ---------------- 2-stage mean-pool + classifier ----------------
__global__ __launch_bounds__(256) void k_pool1(const float* __restrict__ h, float* __restrict__ part) {
    int b = blockIdx.x, g = blockIdx.y, d = threadIdx.x;
    const float* hb = h + ((size_t)b * L_ + g * 128) * DM + d;
    float s = 0.f;
    for (int l = 0; l < 128; l++) s += hb[(size_t)l * DM];
    part[((size_t)b * 16 + g) * DM + d] = s;
}

__global__ __launch_bounds__(256) void k_pool2(const float* __restrict__ part, const float* __restrict__ cw,
                                               const float* __restrict__ cb, float* __restrict__ out) {
    int b = blockIdx.x, tid = threadIdx.x;
    float s = 0.f;
#pragma unroll
    for (int g = 0; g < 16; g++) s += part[((size_t)b * 16 + g) * DM + tid];
    s *= (1.0f / L_);
    float p0 = s * cw[tid];
    float p1 = s * cw[DM + tid];
#pragma unroll
    for (int m = 1; m < 64; m <<= 1) {
        p0 += __shfl_xor(p0, m);
        p1 += __shfl_xor(p1, m);
    }
    __shared__ float r0[4], r1[4];
    if ((tid & 63) == 0) { r0[tid >> 6] = p0; r1[tid >> 6] = p1; }
    __syncthreads();
    if (tid == 0) {
        out[b * 2 + 0] = r0[0] + r0[1] + r0[2] + r0[3] + cb[0];
        out[b * 2 + 1] = r1[0] + r1[1] + r1[2] + r1[3] + cb[1];
    }
}

extern "C" void kernel_launch(void* const* d_in, const int* in_sizes, int n_in,
                              void* d_out, int out_size, void* d_ws, size_t ws_size,
                              hipStream_t stream) {
    const int*   x    = (const int*)d_in[0];
    const float* mask = (const float*)d_in[1];
    const float* emb  = (const float*)d_in[2];
    const float* pos  = (const float*)d_in[3];
    const float* Wi   = (const float*)d_in[4];
    const float* cw   = (const float*)d_in[5];
    const float* cb   = (const float*)d_in[6];
    const float* dtb  = (const float*)d_in[7];
    const float* Alog = (const float*)d_in[8];
    const float* Dp   = (const float*)d_in[9];
    const float* nw   = (const float*)d_in[10];
    const float* Wo   = (const float*)d_in[11];
    const float* lnw  = (const float*)d_in[12];
    const float* lnb  = (const float*)d_in[13];
    const float* clsw = (const float*)d_in[14];
    const float* clsb = (const float*)d_in[15];
    float* out = (float*)d_out;

    float* ws    = (float*)d_ws;
    float* h     = ws;                                   // 16384 x 256
    float* tmp   = h + (size_t)B_ * L_ * DM;             // 16384 x 256
    float* ybuf  = tmp + (size_t)B_ * L_ * DM;           // 16384 x 512
    float* dtraw = ybuf + (size_t)B_ * L_ * DI;          // 16384 x 8
    float* Sg    = dtraw + (size_t)B_ * L_ * NH;         // 64*32*64*16
    float* Pg    = Sg + (size_t)64 * NC * HD * DSZ;      // 2048
    float* cumL  = Pg + (size_t)64 * NC;                 // 64*32*64
    float* Hg    = cumL + (size_t)64 * NC * Q_;          // 64*32*64*16
    float* Cc    = Hg + (size_t)64 * NC * HD * DSZ;      // 16384 x 16
    float* pool  = Cc + (size_t)B_ * L_ * DSZ;           // 8*16*256
    unsigned short* zxb   = (unsigned short*)(pool + (size_t)B_ * 16 * DM);  // 16384 x 1064
    unsigned short* h_bf  = zxb + (size_t)B_ * L_ * DIP;
    unsigned short* yn_bf = h_bf + (size_t)B_ * L_ * DM;
    unsigned short* Wi_bf = yn_bf + (size_t)B_ * L_ * DI;
    unsigned short* Wo_bf = Wi_bf + (size_t)4 * DIP * DM;

    k_f2bf<<<(4 * DIP * DM / 4 + 255) / 256, 256, 0, stream>>>(Wi, Wi_bf, 4 * DIP * DM / 4);
    k_f2bf<<<(4 * DM * DI / 4 + 255) / 256, 256, 0, stream>>>(Wo, Wo_bf, 4 * DM * DI / 4);

    k_embed<<<(B_ * L_ * DM + 255) / 256, 256, 0, stream>>>(x, mask, emb, pos, h, h_bf);

    for (int i = 0; i < 4; i++) {
        // zxbcdt = h @ Wi^T -> bf16 zxb (+ fp32 dtraw cols)
        k_gemm<1><<<dim3(B_ * L_ / 128, (DIP + 127) / 128), 256, 0, stream>>>(
            h_bf, DM, Wi_bf + (size_t)i * DIP * DM, DM, DIP, zxb, DIP, DM, dtraw);
        // fused conv+silu+dt + intra-chunk scan (MFMA)
        k_scan1c<<<dim3(64, NC), 256, 0, stream>>>(
            zxb, dtraw, cw + (size_t)i * CD * 4, cb + i * CD, dtb + i * NH, Alog + i * NH,
            Dp + i * NH, ybuf, Sg, Pg, cumL, Cc);
        k_scan2<<<64, 256, 0, stream>>>(Sg, Pg, Hg);
        // fused cross-chunk + gated RMSNorm -> bf16 yn
        k_scan3g<<<dim3(B_, 128), 256, 0, stream>>>(ybuf, zxb, Hg, cumL, Cc, nw + (size_t)i * DI, yn_bf);
        // out = yn @ Wo^T -> fp32 tmp
        k_gemm<0><<<dim3(B_ * L_ / 128, DM / 128), 256, 0, stream>>>(
            yn_bf, DI, Wo_bf + (size_t)i * DM * DI, DI, DM, tmp, DM, DI, nullptr);
        k_ln<<<B_ * L_, 256, 0, stream>>>(tmp, h, h_bf, lnw, lnb, mask);
    }

    k_pool1<<<dim3(B_, 16), 256, 0, stream>>>(h, pool);
    k_pool2<<<B_, 256, 0, stream>>>(pool, clsw, clsb, out);
}

// Round 6
// 549.772 us; speedup vs baseline: 1.2890x; 1.2890x over previous
//
#include <hip/hip_runtime.h>
#include <hip/hip_bf16.h>
#include <math.h>

#define B_ 8
#define L_ 2048
#define DM 256
#define DIP 1064
#define DI 512
#define CD 544
#define DSZ 16
#define NH 8
#define HD 64
#define Q_ 64
#define NC 32

typedef __attribute__((ext_vector_type(8))) short bf16x8;
typedef __attribute__((ext_vector_type(4))) float f32x4;

__device__ inline unsigned short f2bf(float f) {
    __hip_bfloat16 h = __float2bfloat16(f);
    return *(unsigned short*)&h;
}
__device__ inline float bf2f(unsigned short u) {
    unsigned int x = ((unsigned int)u) << 16;
    return __uint_as_float(x);
}

// ---------------- fp32 -> bf16 bulk convert ----------------
__global__ __launch_bounds__(256) void k_f2bf(const float* __restrict__ in, unsigned short* __restrict__ out, int n4) {
    int i = blockIdx.x * 256 + threadIdx.x;
    if (i >= n4) return;
    float4 v = *(const float4*)(in + (size_t)i * 4);
    ushort4 o;
    o.x = f2bf(v.x); o.y = f2bf(v.y); o.z = f2bf(v.z); o.w = f2bf(v.w);
    *(ushort4*)(out + (size_t)i * 4) = o;
}

// ---------------- embed ----------------
__global__ __launch_bounds__(256) void k_embed(const int* __restrict__ x, const float* __restrict__ mask,
                                               const float* __restrict__ emb, const float* __restrict__ pos,
                                               float* __restrict__ h, unsigned short* __restrict__ h_bf) {
    int i = blockIdx.x * 256 + threadIdx.x;
    if (i >= B_ * L_ * DM) return;
    int d = i % DM;
    int bl = i / DM;
    int l = bl % L_;
    int tok = x[bl];
    float v = (emb[tok * DM + d] + pos[l * DM + d]) * mask[bl];
    h[i] = v;
    h_bf[i] = f2bf(v);
}

// ---------------- bf16 MFMA NT GEMM (128x128 tile, BK=32, global_load_lds) ----------------
// OUTMODE 0: fp32 C.  OUTMODE 1: bf16 C + fp32 dtraw side-buffer for cols >= DI+CD.
template <int OUTMODE>
__global__ __launch_bounds__(256) void k_gemm(const unsigned short* __restrict__ A, int lda,
                                              const unsigned short* __restrict__ Bw, int ldb, int N,
                                              void* __restrict__ Cout, int ldc, int K,
                                              float* __restrict__ dtraw) {
    __shared__ unsigned short Al[2][128 * 32];
    __shared__ unsigned short Bl[2][128 * 32];
    int tid = threadIdx.x;
    int l = tid & 63;
    int w = tid >> 6, wr = w >> 1, wc = w & 1;
    int m0 = blockIdx.x * 128, n0 = blockIdx.y * 128;

    f32x4 zero = {0.f, 0.f, 0.f, 0.f};
    f32x4 acc[4][4];
#pragma unroll
    for (int i = 0; i < 4; i++)
#pragma unroll
        for (int j = 0; j < 4; j++) acc[i][j] = zero;

    int lr = l & 15, kq = l >> 4;
    int aoff = (wr * 64 + lr) * 32 + kq * 8;
    int boff = (wc * 64 + lr) * 32 + kq * 8;

    auto stage = [&](int ks, int buf) {
        int k0 = ks * 32;
#pragma unroll
        for (int q = 0; q < 2; q++) {
            int c = tid + q * 256;
            int row = c >> 2, cc = (c & 3) * 8;
            const unsigned short* ga = A + (size_t)(m0 + row) * lda + k0 + cc;
            __builtin_amdgcn_global_load_lds((const __attribute__((address_space(1))) void*)ga,
                                             (__attribute__((address_space(3))) void*)(&Al[buf][c * 8]), 16, 0, 0);
            int rowb = n0 + row;
            if (rowb > N - 1) rowb = N - 1;
            const unsigned short* gb = Bw + (size_t)rowb * ldb + k0 + cc;
            __builtin_amdgcn_global_load_lds((const __attribute__((address_space(1))) void*)gb,
                                             (__attribute__((address_space(3))) void*)(&Bl[buf][c * 8]), 16, 0, 0);
        }
    };

    stage(0, 0);
    int ksteps = K / 32;
    for (int s = 0; s < ksteps; s++) {
        int buf = s & 1;
        __syncthreads();
        if (s + 1 < ksteps) stage(s + 1, buf ^ 1);
        bf16x8 a[4], b[4];
#pragma unroll
        for (int i = 0; i < 4; i++) a[i] = *(const bf16x8*)&Al[buf][aoff + i * 512];
#pragma unroll
        for (int j = 0; j < 4; j++) b[j] = *(const bf16x8*)&Bl[buf][boff + j * 512];
#pragma unroll
        for (int i = 0; i < 4; i++)
#pragma unroll
            for (int j = 0; j < 4; j++)
                acc[i][j] = __builtin_amdgcn_mfma_f32_16x16x32_bf16(a[i], b[j], acc[i][j], 0, 0, 0);
    }

#pragma unroll
    for (int i = 0; i < 4; i++) {
        int m = m0 + wr * 64 + i * 16 + kq * 4;
#pragma unroll
        for (int j = 0; j < 4; j++) {
            int n = n0 + wc * 64 + j * 16 + lr;
            if (n < N) {
                if (OUTMODE == 0) {
                    float* C = (float*)Cout;
#pragma unroll
                    for (int r = 0; r < 4; r++)
                        C[(size_t)(m + r) * ldc + n] = acc[i][j][r];
                } else {
                    unsigned short* C = (unsigned short*)Cout;
#pragma unroll
                    for (int r = 0; r < 4; r++)
                        C[(size_t)(m + r) * ldc + n] = f2bf(acc[i][j][r]);
                    if (n >= DI + CD) {
#pragma unroll
                        for (int r = 0; r < 4; r++)
                            dtraw[(size_t)(m + r) * NH + (n - (DI + CD))] = acc[i][j][r];
                    }
                }
            }
        }
    }
}

// ---------------- fused conv+silu+dt + chunked scan stage 1 (MFMA) ----------------
__global__ __launch_bounds__(256) void k_scan1c(const unsigned short* __restrict__ zxb,
                                                const float* __restrict__ dtraw,
                                                const float* __restrict__ cw, const float* __restrict__ cb,
                                                const float* __restrict__ dtb, const float* __restrict__ Alog,
                                                const float* __restrict__ Dp,
                                                float* __restrict__ ybuf, float* __restrict__ Sg,
                                                float* __restrict__ Pg, float* __restrict__ cumLg,
                                                float* __restrict__ Cc) {
    int bh = blockIdx.x, c = blockIdx.y;
    int b = bh >> 3, h = bh & 7;
    int tid = threadIdx.x;
    int t0 = c * Q_;
    int w = tid >> 6, l = tid & 63;
    int lr = l & 15, kq = l >> 4;

    __shared__ __align__(16) unsigned short Zl[67 * 96];       // staged zx slice; aliased by Mbf/Btw later
    __shared__ __align__(16) float Xs[Q_][HD];
    __shared__ __align__(16) float Bsf[Q_][DSZ];
    __shared__ __align__(16) float Csf[Q_][DSZ];
    __shared__ __align__(16) unsigned short Xt[Q_ * 72];
    __shared__ __align__(16) unsigned short Cbf[Q_ * 32];
    __shared__ __align__(16) unsigned short Bbf[Q_ * 32];
    __shared__ float Lc[Q_], dts[Q_], coefS[Q_];
    unsigned short* Mbf = Zl;            // 64*64 shorts (after conv phase, Zl is dead)
    unsigned short* Btw = Zl + 4096;     // 16*72 shorts

    float Dval = Dp[h];

    // ---- stage Zl: rows t0-3..t0+63; cols 0..63 = X head slice, 64..95 = B|C ----
    for (int idx = tid; idx < 67 * 12; idx += 256) {
        int rr = idx / 12, seg = idx - rr * 12;
        int lg = t0 - 3 + rr;
        bf16x8 v;
        if (lg >= 0) {
            const unsigned short* src = zxb + (size_t)(b * L_ + lg) * DIP +
                                        (seg < 8 ? (DI + h * HD + seg * 8) : (1024 + (seg - 8) * 8));
            v = *(const bf16x8*)src;
        } else {
#pragma unroll
            for (int j = 0; j < 8; j++) v[j] = 0;
        }
        int col = (seg < 8) ? seg * 8 : (64 + (seg - 8) * 8);
        *(bf16x8*)&Zl[rr * 96 + col] = v;
    }
    // ---- dt / ldA / log-cumsum (wave 0, independent of Zl) ----
    if (tid < 64) {
        float raw = dtraw[(size_t)(b * L_ + t0 + tid) * NH + h] + dtb[h];
        float dtv = (raw > 20.f) ? raw : log1pf(__expf(raw));
        float v = -__expf(Alog[h]) * dtv;
#pragma unroll
        for (int off = 1; off < 64; off <<= 1) {
            float u = __shfl_up(v, off);
            if (tid >= off) v += u;
        }
        dts[tid] = dtv;
        Lc[tid] = v;
        float lend = __shfl(v, 63);
        coefS[tid] = __expf(lend - v) * dtv;
        cumLg[(size_t)(bh * NC + c) * Q_ + tid] = v;
        if (tid == 63) Pg[bh * NC + c] = __expf(v);
    }
    __syncthreads();

    // ---- depthwise conv (k=4) + bias + silu -> Xs / Bsf / Csf ----
    for (int idx = tid; idx < Q_ * 96; idx += 256) {
        int t = idx / 96, ch = idx - t * 96;
        int cc = (ch < 64) ? (h * HD + ch) : (DI + (ch - 64));
        float acc = cb[cc];
#pragma unroll
        for (int k = 0; k < 4; k++)
            acc = fmaf(bf2f(Zl[(t + k) * 96 + ch]), cw[cc * 4 + k], acc);
        float s = acc / (1.f + __expf(-acc));
        if (ch < 64) Xs[t][ch] = s;
        else if (ch < 80) Bsf[t][ch - 64] = s;
        else Csf[t][ch - 80] = s;
    }
    __syncthreads();

    // ---- build bf16 operands (Zl is dead from here; Mbf/Btw alias it) ----
    {   // Cbf / Bbf (K padded to 32, dt folded into B), kblk-swizzled by row&3
        int t = tid & 63, kb = tid >> 6;
        int swz = (kb ^ (t & 3)) * 8;
        bf16x8 cv, bv;
        float dtv = dts[t];
#pragma unroll
        for (int j = 0; j < 8; j++) {
            int k = kb * 8 + j;
            float cf = (k < DSZ) ? Csf[t][k] : 0.f;
            float bf = (k < DSZ) ? dtv * Bsf[t][k] : 0.f;
            cv[j] = (short)f2bf(cf);
            bv[j] = (short)f2bf(bf);
        }
        *(bf16x8*)&Cbf[t * 32 + swz] = cv;
        *(bf16x8*)&Bbf[t * 32 + swz] = bv;
    }
    {   // Xt[p][s] = bf16(X[s][p])
        int p = tid & 63, sb = tid >> 6;
        bf16x8 lo, hi;
#pragma unroll
        for (int j = 0; j < 8; j++) {
            lo[j] = (short)f2bf(Xs[sb * 16 + j][p]);
            hi[j] = (short)f2bf(Xs[sb * 16 + 8 + j][p]);
        }
        *(bf16x8*)&Xt[p * 72 + sb * 16] = lo;
        *(bf16x8*)&Xt[p * 72 + sb * 16 + 8] = hi;
    }
    if (tid < 128) {   // Btw[n][s] = bf16(coefS[s] * B[s][n])
        int n = tid >> 3, sb = tid & 7;
        bf16x8 v;
#pragma unroll
        for (int j = 0; j < 8; j++) {
            int s = sb * 8 + j;
            v[j] = (short)f2bf(coefS[s] * Bsf[s][n]);
        }
        *(bf16x8*)&Btw[n * 72 + sb * 8] = v;
    }
    if (h == 0) {      // compact C for scan3g (shared across heads)
        int t = tid >> 2, n0 = (tid & 3) * 4;
        *(float4*)(Cc + ((size_t)(b * L_ + t0 + t)) * DSZ + n0) = *(const float4*)&Csf[t][n0];
    }
    __syncthreads();

    f32x4 zero = {0.f, 0.f, 0.f, 0.f};

    // phase 1: CB tiles (wave w owns t-tile w), K=32 (zero-padded)
    f32x4 cbt[4];
    {
        bf16x8 af = *(const bf16x8*)&Cbf[(w * 16 + lr) * 32 + ((kq ^ (lr & 3)) * 8)];
#pragma unroll
        for (int st = 0; st < 4; st++) {
            bf16x8 bf = *(const bf16x8*)&Bbf[(st * 16 + lr) * 32 + ((kq ^ (lr & 3)) * 8)];
            cbt[st] = __builtin_amdgcn_mfma_f32_16x16x32_bf16(af, bf, zero, 0, 0, 0);
        }
    }
    // mask + decay -> Mbf
#pragma unroll
    for (int st = 0; st < 4; st++) {
#pragma unroll
        for (int r = 0; r < 4; r++) {
            int t = w * 16 + kq * 4 + r;
            int s = st * 16 + lr;
            float m = (s <= t) ? __expf(Lc[t] - Lc[s]) * cbt[st][r] : 0.f;
            Mbf[t * 64 + (((s >> 3) ^ (t & 7)) * 8) + (s & 7)] = f2bf(m);
        }
    }
    __syncthreads();

    // phase 2: Y = M * X (+ D*x), write to ybuf
    {
        float* base_y = ybuf + ((size_t)b * L_ + t0) * DI + h * HD;
        f32x4 acc[4];
#pragma unroll
        for (int pt = 0; pt < 4; pt++) acc[pt] = zero;
#pragma unroll
        for (int ks = 0; ks < 2; ks++) {
            bf16x8 af = *(const bf16x8*)&Mbf[(w * 16 + lr) * 64 + (((ks * 4 + kq) ^ (lr & 7)) * 8)];
#pragma unroll
            for (int pt = 0; pt < 4; pt++) {
                bf16x8 bf = *(const bf16x8*)&Xt[(pt * 16 + lr) * 72 + ks * 32 + kq * 8];
                acc[pt] = __builtin_amdgcn_mfma_f32_16x16x32_bf16(af, bf, acc[pt], 0, 0, 0);
            }
        }
#pragma unroll
        for (int pt = 0; pt < 4; pt++) {
#pragma unroll
            for (int r = 0; r < 4; r++) {
                int t = w * 16 + kq * 4 + r;
                int p = pt * 16 + lr;
                base_y[(size_t)t * DI + p] = acc[pt][r] + Dval * Xs[t][p];
            }
        }
    }

    // phase 3: chunk state S = X^T * (coef*B)
    {
        f32x4 sacc = zero;
#pragma unroll
        for (int ks = 0; ks < 2; ks++) {
            bf16x8 af = *(const bf16x8*)&Xt[(w * 16 + lr) * 72 + ks * 32 + kq * 8];
            bf16x8 bf = *(const bf16x8*)&Btw[lr * 72 + ks * 32 + kq * 8];
            sacc = __builtin_amdgcn_mfma_f32_16x16x32_bf16(af, bf, sacc, 0, 0, 0);
        }
#pragma unroll
        for (int r = 0; r < 4; r++) {
            int p = w * 16 + kq * 4 + r;
            Sg[((size_t)(bh * NC + c) * HD + p) * DSZ + lr] = sacc[r];
        }
    }
}

// ---------------- chunked scan stage 2 ----------------
__global__ __launch_bounds__(256) void k_scan2(const float* __restrict__ Sg, const float* __restrict__ Pg,
                                               float* __restrict__ Hg) {
    int bh = blockIdx.x;
    int tid = threadIdx.x;
    int p = tid >> 2, n0 = (tid & 3) * 4;
    float4 H = make_float4(0.f, 0.f, 0.f, 0.f);
    for (int c = 0; c < NC; c++) {
        size_t base = ((size_t)(bh * NC + c) * HD + p) * DSZ + n0;
        float P = Pg[bh * NC + c];
        float4 S = *(const float4*)(Sg + base);
        *(float4*)(Hg + base) = H;
        H.x = fmaf(P, H.x, S.x);
        H.y = fmaf(P, H.y, S.y);
        H.z = fmaf(P, H.z, S.z);
        H.w = fmaf(P, H.w, S.w);
    }
}

// ---------------- fused scan stage 3 + gated RMSNorm -> bf16 yn ----------------
// grid (B_, 128): block handles 16 rows x all 512 channels.
// LDS layout Hsn[n][p][hh] with hh-stride 9 -> 2-way (free) bank aliasing.
__global__ __launch_bounds__(256) void k_scan3g(const float* __restrict__ ybuf,
                                                const unsigned short* __restrict__ zxb,
                                                const float* __restrict__ Hg, const float* __restrict__ cumLg,
                                                const float* __restrict__ Cc, const float* __restrict__ nw,
                                                unsigned short* __restrict__ yn_bf) {
    int b = blockIdx.x, by = blockIdx.y;
    int c64 = by >> 2, tl0 = (by & 3) * 16;
    int t0 = by * 16;
    int tid = threadIdx.x;
    __shared__ float Hsn[DSZ * 576];   // n*576 + p*9 + hh  (36 KB)
    __shared__ float Lq[NH][16];

    {   // load H states: thread handles p = tid&63, heads {2*(tid>>6), 2*(tid>>6)+1}
        int p = tid & 63, hp = tid >> 6;
#pragma unroll
        for (int ho = 0; ho < 2; ho++) {
            int hh = hp * 2 + ho;
            const float* src = Hg + (((size_t)(b * NH + hh) * NC + c64) * HD + p) * DSZ;
            float* dst = &Hsn[p * 9 + hh];
#pragma unroll
            for (int nq = 0; nq < 4; nq++) {
                float4 v = *(const float4*)(src + nq * 4);
                dst[(nq * 4 + 0) * 576] = v.x;
                dst[(nq * 4 + 1) * 576] = v.y;
                dst[(nq * 4 + 2) * 576] = v.z;
                dst[(nq * 4 + 3) * 576] = v.w;
            }
        }
    }
    if (tid < 128) {
        int hh = tid >> 4, t = tid & 15;
        Lq[hh][t] = cumLg[((size_t)(b * NH + hh) * NC + c64) * Q_ + tl0 + t];
    }
    __syncthreads();

    int t = tid >> 4, q = tid & 15;
    int hh = q >> 1, p0 = (q & 1) * 32;
    size_t bl = (size_t)b * L_ + t0 + t;
    float ef = __expf(Lq[hh][t]);

    // Cr[n] = ef * C[t][n] in registers (16 lanes share row t -> broadcast loads)
    float Cr[16];
#pragma unroll
    for (int k = 0; k < 4; k++) {
        float4 v = *(const float4*)(Cc + bl * DSZ + k * 4);
        Cr[4 * k + 0] = ef * v.x;
        Cr[4 * k + 1] = ef * v.y;
        Cr[4 * k + 2] = ef * v.z;
        Cr[4 * k + 3] = ef * v.w;
    }

    const float* yrow = ybuf + bl * DI + hh * HD + p0;
    const unsigned short* zrow = zxb + bl * DIP + hh * HD + p0;
    float yv[32];
    unsigned short zv[32];
#pragma unroll
    for (int k = 0; k < 8; k++) *(float4*)&yv[k * 4] = *(const float4*)(yrow + k * 4);
#pragma unroll
    for (int k = 0; k < 4; k++) *(bf16x8*)&zv[k * 8] = *(const bf16x8*)(zrow + k * 8);

    float yg[32];
    float ss = 0.f;
#pragma unroll
    for (int j = 0; j < 32; j++) {
        const float* hp_ = &Hsn[(p0 + j) * 9 + hh];
        float d = 0.f;
#pragma unroll
        for (int n = 0; n < DSZ; n++) d = fmaf(Cr[n], hp_[n * 576], d);
        float y = yv[j] + d;
        float z = bf2f(zv[j]);
        float g = z / (1.f + __expf(-z));
        yg[j] = y * g;
        ss = fmaf(yg[j], yg[j], ss);
    }
    ss += __shfl_xor(ss, 1);
    ss += __shfl_xor(ss, 2);
    ss += __shfl_xor(ss, 4);
    ss += __shfl_xor(ss, 8);
    float r = rsqrtf(ss * (1.f / DI) + 1e-5f);

    const float* nwp = nw + hh * HD + p0;
    unsigned short* dst = yn_bf + bl * DI + hh * HD + p0;
#pragma unroll
    for (int k = 0; k < 4; k++) {
        bf16x8 o;
#pragma unroll
        for (int j = 0; j < 8; j++) o[j] = (short)f2bf(yg[k * 8 + j] * r * nwp[k * 8 + j]);
        *(bf16x8*)(dst + k * 8) = o;
    }
}

// ---------------- residual add + LayerNorm + mask (+ bf16 copy) ----------------
__global__ __launch_bounds__(256) void k_ln(const float* __restrict__ tmp, float* __restrict__ h,
                                            unsigned short* __restrict__ h_bf,
                                            const float* __restrict__ lnw, const float* __restrict__ lnb,
                                            const float* __restrict__ mask) {
    int bl = blockIdx.x;
    int tid = threadIdx.x;
    size_t idx = (size_t)bl * DM + tid;
    float v = tmp[idx] + h[idx];
    __shared__ float red[4];
    float s = v;
#pragma unroll
    for (int m = 1; m < 64; m <<= 1) s += __shfl_xor(s, m);
    if ((tid & 63) == 0) red[tid >> 6] = s;
    __syncthreads();
    float mu = (red[0] + red[1] + red[2] + red[3]) * (1.f / DM);
    float d = v - mu;
    float q = d * d;
    __syncthreads();
#pragma unroll
    for (int m = 1; m < 64; m <<= 1) q += __shfl_xor(q, m);
    if ((tid & 63) == 0) red[tid >> 6] = q;
    __syncthreads();
    float var = (red[0] + red[1] + red[2] + red[3]) * (1.f / DM);
    float o = (d * rsqrtf(var + 1e-5f) * lnw[tid] + lnb[tid]) * mask[bl];
    h[idx] = o;
    h_bf[idx] = f2bf(o);
}

// ---------------- 2-stage mean-pool + classifier ----------------
__global__ __launch_bounds__(256) void k_pool1(const float* __restrict__ h, float* __restrict__ part) {
    int b = blockIdx.x, g = blockIdx.y, d = threadIdx.x;
    const float* hb = h + ((size_t)b * L_ + g * 128) * DM + d;
    float s = 0.f;
    for (int l = 0; l < 128; l++) s += hb[(size_t)l * DM];
    part[((size_t)b * 16 + g) * DM + d] = s;
}

__global__ __launch_bounds__(256) void k_pool2(const float* __restrict__ part, const float* __restrict__ cw,
                                               const float* __restrict__ cb, float* __restrict__ out) {
    int b = blockIdx.x, tid = threadIdx.x;
    float s = 0.f;
#pragma unroll
    for (int g = 0; g < 16; g++) s += part[((size_t)b * 16 + g) * DM + tid];
    s *= (1.0f / L_);
    float p0 = s * cw[tid];
    float p1 = s * cw[DM + tid];
#pragma unroll
    for (int m = 1; m < 64; m <<= 1) {
        p0 += __shfl_xor(p0, m);
        p1 += __shfl_xor(p1, m);
    }
    __shared__ float r0[4], r1[4];
    if ((tid & 63) == 0) { r0[tid >> 6] = p0; r1[tid >> 6] = p1; }
    __syncthreads();
    if (tid == 0) {
        out[b * 2 + 0] = r0[0] + r0[1] + r0[2] + r0[3] + cb[0];
        out[b * 2 + 1] = r1[0] + r1[1] + r1[2] + r1[3] + cb[1];
    }
}

extern "C" void kernel_launch(void* const* d_in, const int* in_sizes, int n_in,
                              void* d_out, int out_size, void* d_ws, size_t ws_size,
                              hipStream_t stream) {
    const int*   x    = (const int*)d_in[0];
    const float* mask = (const float*)d_in[1];
    const float* emb  = (const float*)d_in[2];
    const float* pos  = (const float*)d_in[3];
    const float* Wi   = (const float*)d_in[4];
    const float* cw   = (const float*)d_in[5];
    const float* cb   = (const float*)d_in[6];
    const float* dtb  = (const float*)d_in[7];
    const float* Alog = (const float*)d_in[8];
    const float* Dp   = (const float*)d_in[9];
    const float* nw   = (const float*)d_in[10];
    const float* Wo   = (const float*)d_in[11];
    const float* lnw  = (const float*)d_in[12];
    const float* lnb  = (const float*)d_in[13];
    const float* clsw = (const float*)d_in[14];
    const float* clsb = (const float*)d_in[15];
    float* out = (float*)d_out;

    float* ws    = (float*)d_ws;
    float* h     = ws;                                   // 16384 x 256
    float* tmp   = h + (size_t)B_ * L_ * DM;             // 16384 x 256
    float* ybuf  = tmp + (size_t)B_ * L_ * DM;           // 16384 x 512
    float* dtraw = ybuf + (size_t)B_ * L_ * DI;          // 16384 x 8
    float* Sg    = dtraw + (size_t)B_ * L_ * NH;         // 64*32*64*16
    float* Pg    = Sg + (size_t)64 * NC * HD * DSZ;      // 2048
    float* cumL  = Pg + (size_t)64 * NC;                 // 64*32*64
    float* Hg    = cumL + (size_t)64 * NC * Q_;          // 64*32*64*16
    float* Cc    = Hg + (size_t)64 * NC * HD * DSZ;      // 16384 x 16
    float* pool  = Cc + (size_t)B_ * L_ * DSZ;           // 8*16*256
    unsigned short* zxb   = (unsigned short*)(pool + (size_t)B_ * 16 * DM);  // 16384 x 1064
    unsigned short* h_bf  = zxb + (size_t)B_ * L_ * DIP;
    unsigned short* yn_bf = h_bf + (size_t)B_ * L_ * DM;
    unsigned short* Wi_bf = yn_bf + (size_t)B_ * L_ * DI;
    unsigned short* Wo_bf = Wi_bf + (size_t)4 * DIP * DM;

    k_f2bf<<<(4 * DIP * DM / 4 + 255) / 256, 256, 0, stream>>>(Wi, Wi_bf, 4 * DIP * DM / 4);
    k_f2bf<<<(4 * DM * DI / 4 + 255) / 256, 256, 0, stream>>>(Wo, Wo_bf, 4 * DM * DI / 4);

    k_embed<<<(B_ * L_ * DM + 255) / 256, 256, 0, stream>>>(x, mask, emb, pos, h, h_bf);

    for (int i = 0; i < 4; i++) {
        // zxbcdt = h @ Wi^T -> bf16 zxb (+ fp32 dtraw cols)
        k_gemm<1><<<dim3(B_ * L_ / 128, (DIP + 127) / 128), 256, 0, stream>>>(
            h_bf, DM, Wi_bf + (size_t)i * DIP * DM, DM, DIP, zxb, DIP, DM, dtraw);
        // fused conv+silu+dt + intra-chunk scan (MFMA)
        k_scan1c<<<dim3(64, NC), 256, 0, stream>>>(
            zxb, dtraw, cw + (size_t)i * CD * 4, cb + i * CD, dtb + i * NH, Alog + i * NH,
            Dp + i * NH, ybuf, Sg, Pg, cumL, Cc);
        k_scan2<<<64, 256, 0, stream>>>(Sg, Pg, Hg);
        // fused cross-chunk + gated RMSNorm -> bf16 yn
        k_scan3g<<<dim3(B_, 128), 256, 0, stream>>>(ybuf, zxb, Hg, cumL, Cc, nw + (size_t)i * DI, yn_bf);
        // out = yn @ Wo^T -> fp32 tmp
        k_gemm<0><<<dim3(B_ * L_ / 128, DM / 128), 256, 0, stream>>>(
            yn_bf, DI, Wo_bf + (size_t)i * DM * DI, DI, DM, tmp, DM, DI, nullptr);
        k_ln<<<B_ * L_, 256, 0, stream>>>(tmp, h, h_bf, lnw, lnb, mask);
    }

    k_pool1<<<dim3(B_, 16), 256, 0, stream>>>(h, pool);
    k_pool2<<<B_, 256, 0, stream>>>(pool, clsw, clsb, out);
}

// Round 8
// 521.922 us; speedup vs baseline: 1.3578x; 1.0534x over previous
//
#include <hip/hip_runtime.h>
#include <hip/hip_bf16.h>
#include <math.h>

#define B_ 8
#define L_ 2048
#define DM 256
#define DIP 1064
#define DI 512
#define CD 544
#define DSZ 16
#define NH 8
#define HD 64
#define Q_ 64
#define NC 32

typedef __attribute__((ext_vector_type(8))) short bf16x8;
typedef __attribute__((ext_vector_type(4))) float f32x4;

__device__ inline unsigned short f2bf(float f) {
    __hip_bfloat16 h = __float2bfloat16(f);
    return *(unsigned short*)&h;
}
__device__ inline float bf2f(unsigned short u) {
    unsigned int x = ((unsigned int)u) << 16;
    return __uint_as_float(x);
}

// ---------------- fp32 -> bf16 bulk convert ----------------
__global__ __launch_bounds__(256) void k_f2bf(const float* __restrict__ in, unsigned short* __restrict__ out, int n4) {
    int i = blockIdx.x * 256 + threadIdx.x;
    if (i >= n4) return;
    float4 v = *(const float4*)(in + (size_t)i * 4);
    ushort4 o;
    o.x = f2bf(v.x); o.y = f2bf(v.y); o.z = f2bf(v.z); o.w = f2bf(v.w);
    *(ushort4*)(out + (size_t)i * 4) = o;
}

// ---------------- embed ----------------
__global__ __launch_bounds__(256) void k_embed(const int* __restrict__ x, const float* __restrict__ mask,
                                               const float* __restrict__ emb, const float* __restrict__ pos,
                                               float* __restrict__ h, unsigned short* __restrict__ h_bf) {
    int i = blockIdx.x * 256 + threadIdx.x;
    if (i >= B_ * L_ * DM) return;
    int d = i % DM;
    int bl = i / DM;
    int l = bl % L_;
    int tok = x[bl];
    float v = (emb[tok * DM + d] + pos[l * DM + d]) * mask[bl];
    h[i] = v;
    h_bf[i] = f2bf(v);
}

// ---------------- bf16 MFMA NT GEMM (128x128 tile, BK=32, global_load_lds) ----------------
// OUTMODE 0: fp32 C.  OUTMODE 1: bf16 C + fp32 dtraw side-buffer for cols >= DI+CD.
template <int OUTMODE>
__global__ __launch_bounds__(256) void k_gemm(const unsigned short* __restrict__ A, int lda,
                                              const unsigned short* __restrict__ Bw, int ldb, int N,
                                              void* __restrict__ Cout, int ldc, int K,
                                              float* __restrict__ dtraw) {
    __shared__ unsigned short Al[2][128 * 32];
    __shared__ unsigned short Bl[2][128 * 32];
    int tid = threadIdx.x;
    int l = tid & 63;
    int w = tid >> 6, wr = w >> 1, wc = w & 1;
    int m0 = blockIdx.x * 128, n0 = blockIdx.y * 128;

    f32x4 zero = {0.f, 0.f, 0.f, 0.f};
    f32x4 acc[4][4];
#pragma unroll
    for (int i = 0; i < 4; i++)
#pragma unroll
        for (int j = 0; j < 4; j++) acc[i][j] = zero;

    int lr = l & 15, kq = l >> 4;
    int aoff = (wr * 64 + lr) * 32 + kq * 8;
    int boff = (wc * 64 + lr) * 32 + kq * 8;

    auto stage = [&](int ks, int buf) {
        int k0 = ks * 32;
#pragma unroll
        for (int q = 0; q < 2; q++) {
            int c = tid + q * 256;
            int row = c >> 2, cc = (c & 3) * 8;
            const unsigned short* ga = A + (size_t)(m0 + row) * lda + k0 + cc;
            __builtin_amdgcn_global_load_lds((const __attribute__((address_space(1))) void*)ga,
                                             (__attribute__((address_space(3))) void*)(&Al[buf][c * 8]), 16, 0, 0);
            int rowb = n0 + row;
            if (rowb > N - 1) rowb = N - 1;
            const unsigned short* gb = Bw + (size_t)rowb * ldb + k0 + cc;
            __builtin_amdgcn_global_load_lds((const __attribute__((address_space(1))) void*)gb,
                                             (__attribute__((address_space(3))) void*)(&Bl[buf][c * 8]), 16, 0, 0);
        }
    };

    stage(0, 0);
    int ksteps = K / 32;
    for (int s = 0; s < ksteps; s++) {
        int buf = s & 1;
        __syncthreads();
        if (s + 1 < ksteps) stage(s + 1, buf ^ 1);
        bf16x8 a[4], b[4];
#pragma unroll
        for (int i = 0; i < 4; i++) a[i] = *(const bf16x8*)&Al[buf][aoff + i * 512];
#pragma unroll
        for (int j = 0; j < 4; j++) b[j] = *(const bf16x8*)&Bl[buf][boff + j * 512];
#pragma unroll
        for (int i = 0; i < 4; i++)
#pragma unroll
            for (int j = 0; j < 4; j++)
                acc[i][j] = __builtin_amdgcn_mfma_f32_16x16x32_bf16(a[i], b[j], acc[i][j], 0, 0, 0);
    }

#pragma unroll
    for (int i = 0; i < 4; i++) {
        int m = m0 + wr * 64 + i * 16 + kq * 4;
#pragma unroll
        for (int j = 0; j < 4; j++) {
            int n = n0 + wc * 64 + j * 16 + lr;
            if (n < N) {
                if (OUTMODE == 0) {
                    float* C = (float*)Cout;
#pragma unroll
                    for (int r = 0; r < 4; r++)
                        C[(size_t)(m + r) * ldc + n] = acc[i][j][r];
                } else {
                    unsigned short* C = (unsigned short*)Cout;
#pragma unroll
                    for (int r = 0; r < 4; r++)
                        C[(size_t)(m + r) * ldc + n] = f2bf(acc[i][j][r]);
                    if (n >= DI + CD) {
#pragma unroll
                        for (int r = 0; r < 4; r++)
                            dtraw[(size_t)(m + r) * NH + (n - (DI + CD))] = acc[i][j][r];
                    }
                }
            }
        }
    }
}

// ---------------- fused conv+silu+dt + chunked scan stage 1 (MFMA) ----------------
// Conv writes bf16 MFMA operands directly; fp32 Xs kept for exact D*x epilogue.
// Btw has its OWN LDS (no Zl alias -> no race); Mbf aliases Zl only after conv barrier.
__global__ __launch_bounds__(256) void k_scan1c(const unsigned short* __restrict__ zxb,
                                                const float* __restrict__ dtraw,
                                                const float* __restrict__ cw, const float* __restrict__ cb,
                                                const float* __restrict__ dtb, const float* __restrict__ Alog,
                                                const float* __restrict__ Dp,
                                                float* __restrict__ ybuf, float* __restrict__ Sg,
                                                float* __restrict__ Pg, float* __restrict__ cumLg,
                                                float* __restrict__ Cc) {
    int bh = blockIdx.x, c = blockIdx.y;
    int b = bh >> 3, h = bh & 7;
    int tid = threadIdx.x;
    int t0 = c * Q_;
    int w = tid >> 6, l = tid & 63;
    int lr = l & 15, kq = l >> 4;

    __shared__ __align__(16) unsigned short Zl[67 * 96];     // 12.6 KB staged zx; aliased by Mbf after conv
    __shared__ __align__(16) float Xs[Q_][HD];               // 16 KB fp32 X (D*x epilogue)
    __shared__ __align__(16) unsigned short Xt[Q_ * 72];     // 9.2 KB  X^T [p][s]
    __shared__ __align__(16) unsigned short Cbf[Q_ * 32];    // 4 KB
    __shared__ __align__(16) unsigned short Bbf[Q_ * 32];    // 4 KB
    __shared__ __align__(16) unsigned short Btw[DSZ * 72];   // 2.25 KB (dedicated, no alias)
    __shared__ float Lc[Q_], dts[Q_], coefS[Q_];
    unsigned short* Mbf = Zl;            // 64*64 shorts (8 KB), Zl dead after conv barrier

    float Dval = Dp[h];

    // ---- stage Zl: rows t0-3..t0+63; cols 0..63 = X head slice, 64..95 = B|C ----
    for (int idx = tid; idx < 67 * 12; idx += 256) {
        int rr = idx / 12, seg = idx - rr * 12;
        int lg = t0 - 3 + rr;
        bf16x8 v;
        if (lg >= 0) {
            const unsigned short* src = zxb + (size_t)(b * L_ + lg) * DIP +
                                        (seg < 8 ? (DI + h * HD + seg * 8) : (1024 + (seg - 8) * 8));
            v = *(const bf16x8*)src;
        } else {
#pragma unroll
            for (int j = 0; j < 8; j++) v[j] = 0;
        }
        int col = (seg < 8) ? seg * 8 : (64 + (seg - 8) * 8);
        *(bf16x8*)&Zl[rr * 96 + col] = v;
    }
    // ---- zero-fill Cbf/Bbf K-pad ----
    {
        bf16x8 z8;
#pragma unroll
        for (int j = 0; j < 8; j++) z8[j] = 0;
        *(bf16x8*)&Cbf[tid * 8] = z8;
        *(bf16x8*)&Bbf[tid * 8] = z8;
    }
    // ---- dt / ldA / log-cumsum (wave 0) ----
    if (tid < 64) {
        float raw = dtraw[(size_t)(b * L_ + t0 + tid) * NH + h] + dtb[h];
        float dtv = (raw > 20.f) ? raw : log1pf(__expf(raw));
        float v = -__expf(Alog[h]) * dtv;
#pragma unroll
        for (int off = 1; off < 64; off <<= 1) {
            float u = __shfl_up(v, off);
            if (tid >= off) v += u;
        }
        dts[tid] = dtv;
        Lc[tid] = v;
        float lend = __shfl(v, 63);
        coefS[tid] = __expf(lend - v) * dtv;
        cumLg[(size_t)(bh * NC + c) * Q_ + tid] = v;
        if (tid == 63) Pg[bh * NC + c] = __expf(v);
    }
    __syncthreads();

    // ---- depthwise conv (k=4) + bias + silu -> operands directly ----
    for (int idx = tid; idx < Q_ * 96; idx += 256) {
        int t = idx / 96, ch = idx - t * 96;
        int cc = (ch < 64) ? (h * HD + ch) : (DI + (ch - 64));
        float acc = cb[cc];
#pragma unroll
        for (int k = 0; k < 4; k++)
            acc = fmaf(bf2f(Zl[(t + k) * 96 + ch]), cw[cc * 4 + k], acc);
        float s = acc / (1.f + __expf(-acc));
        if (ch < 64) {
            Xs[t][ch] = s;
            Xt[ch * 72 + t] = f2bf(s);
        } else if (ch < 80) {
            int n = ch - 64;
            Bbf[t * 32 + (((n >> 3) ^ (t & 3)) * 8) + (n & 7)] = f2bf(dts[t] * s);
            Btw[n * 72 + t] = f2bf(coefS[t] * s);
        } else {
            int n = ch - 80;
            Cbf[t * 32 + (((n >> 3) ^ (t & 3)) * 8) + (n & 7)] = f2bf(s);
            if (h == 0) Cc[((size_t)(b * L_ + t0 + t)) * DSZ + n] = s;
        }
    }
    __syncthreads();

    f32x4 zero = {0.f, 0.f, 0.f, 0.f};

    // phase 1: CB tiles (wave w owns t-tile w), K=32 (zero-padded)
    f32x4 cbt[4];
    {
        bf16x8 af = *(const bf16x8*)&Cbf[(w * 16 + lr) * 32 + ((kq ^ (lr & 3)) * 8)];
#pragma unroll
        for (int st = 0; st < 4; st++) {
            bf16x8 bf = *(const bf16x8*)&Bbf[(st * 16 + lr) * 32 + ((kq ^ (lr & 3)) * 8)];
            cbt[st] = __builtin_amdgcn_mfma_f32_16x16x32_bf16(af, bf, zero, 0, 0, 0);
        }
    }
    // mask + decay -> Mbf (aliases Zl, dead now)
#pragma unroll
    for (int st = 0; st < 4; st++) {
#pragma unroll
        for (int r = 0; r < 4; r++) {
            int t = w * 16 + kq * 4 + r;
            int s = st * 16 + lr;
            float m = (s <= t) ? __expf(Lc[t] - Lc[s]) * cbt[st][r] : 0.f;
            Mbf[t * 64 + (((s >> 3) ^ (t & 7)) * 8) + (s & 7)] = f2bf(m);
        }
    }
    __syncthreads();

    // phase 2: Y = M * X + D*x (fp32 epilogue) -> fp32 ybuf
    {
        float* base_y = ybuf + ((size_t)b * L_ + t0) * DI + h * HD;
        f32x4 acc[4];
#pragma unroll
        for (int pt = 0; pt < 4; pt++) acc[pt] = zero;
#pragma unroll
        for (int ks = 0; ks < 2; ks++) {
            bf16x8 af = *(const bf16x8*)&Mbf[(w * 16 + lr) * 64 + (((ks * 4 + kq) ^ (lr & 7)) * 8)];
#pragma unroll
            for (int pt = 0; pt < 4; pt++) {
                bf16x8 bf = *(const bf16x8*)&Xt[(pt * 16 + lr) * 72 + ks * 32 + kq * 8];
                acc[pt] = __builtin_amdgcn_mfma_f32_16x16x32_bf16(af, bf, acc[pt], 0, 0, 0);
            }
        }
#pragma unroll
        for (int pt = 0; pt < 4; pt++) {
#pragma unroll
            for (int r = 0; r < 4; r++) {
                int t = w * 16 + kq * 4 + r;
                int p = pt * 16 + lr;
                base_y[(size_t)t * DI + p] = acc[pt][r] + Dval * Xs[t][p];
            }
        }
    }

    // phase 3: chunk state S = X^T * (coef*B)
    {
        f32x4 sacc = zero;
#pragma unroll
        for (int ks = 0; ks < 2; ks++) {
            bf16x8 af = *(const bf16x8*)&Xt[(w * 16 + lr) * 72 + ks * 32 + kq * 8];
            bf16x8 bf = *(const bf16x8*)&Btw[lr * 72 + ks * 32 + kq * 8];
            sacc = __builtin_amdgcn_mfma_f32_16x16x32_bf16(af, bf, sacc, 0, 0, 0);
        }
#pragma unroll
        for (int r = 0; r < 4; r++) {
            int p = w * 16 + kq * 4 + r;
            Sg[((size_t)(bh * NC + c) * HD + p) * DSZ + lr] = sacc[r];
        }
    }
}

// ---------------- chunked scan stage 2 ----------------
__global__ __launch_bounds__(256) void k_scan2(const float* __restrict__ Sg, const float* __restrict__ Pg,
                                               float* __restrict__ Hg) {
    int bh = blockIdx.x;
    int tid = threadIdx.x;
    int p = tid >> 2, n0 = (tid & 3) * 4;
    float4 H = make_float4(0.f, 0.f, 0.f, 0.f);
    for (int c = 0; c < NC; c++) {
        size_t base = ((size_t)(bh * NC + c) * HD + p) * DSZ + n0;
        float P = Pg[bh * NC + c];
        float4 S = *(const float4*)(Sg + base);
        *(float4*)(Hg + base) = H;
        H.x = fmaf(P, H.x, S.x);
        H.y = fmaf(P, H.y, S.y);
        H.z = fmaf(P, H.z, S.z);
        H.w = fmaf(P, H.w, S.w);
    }
}

// ---------------- fused scan stage 3 + gated RMSNorm -> bf16 yn ----------------
__global__ __launch_bounds__(256) void k_scan3g(const float* __restrict__ ybuf,
                                                const unsigned short* __restrict__ zxb,
                                                const float* __restrict__ Hg, const float* __restrict__ cumLg,
                                                const float* __restrict__ Cc, const float* __restrict__ nw,
                                                unsigned short* __restrict__ yn_bf) {
    int b = blockIdx.x, by = blockIdx.y;
    int c64 = by >> 2, tl0 = (by & 3) * 16;
    int t0 = by * 16;
    int tid = threadIdx.x;
    __shared__ float Hsn[DSZ * 576];   // n*576 + p*9 + hh  (36 KB)
    __shared__ float Lq[NH][16];

    {
        int p = tid & 63, hp = tid >> 6;
#pragma unroll
        for (int ho = 0; ho < 2; ho++) {
            int hh = hp * 2 + ho;
            const float* src = Hg + (((size_t)(b * NH + hh) * NC + c64) * HD + p) * DSZ;
            float* dst = &Hsn[p * 9 + hh];
#pragma unroll
            for (int nq = 0; nq < 4; nq++) {
                float4 v = *(const float4*)(src + nq * 4);
                dst[(nq * 4 + 0) * 576] = v.x;
                dst[(nq * 4 + 1) * 576] = v.y;
                dst[(nq * 4 + 2) * 576] = v.z;
                dst[(nq * 4 + 3) * 576] = v.w;
            }
        }
    }
    if (tid < 128) {
        int hh = tid >> 4, t = tid & 15;
        Lq[hh][t] = cumLg[((size_t)(b * NH + hh) * NC + c64) * Q_ + tl0 + t];
    }
    __syncthreads();

    int t = tid >> 4, q = tid & 15;
    int hh = q >> 1, p0 = (q & 1) * 32;
    size_t bl = (size_t)b * L_ + t0 + t;
    float ef = __expf(Lq[hh][t]);

    float Cr[16];
#pragma unroll
    for (int k = 0; k < 4; k++) {
        float4 v = *(const float4*)(Cc + bl * DSZ + k * 4);
        Cr[4 * k + 0] = ef * v.x;
        Cr[4 * k + 1] = ef * v.y;
        Cr[4 * k + 2] = ef * v.z;
        Cr[4 * k + 3] = ef * v.w;
    }

    const float* yrow = ybuf + bl * DI + hh * HD + p0;
    const unsigned short* zrow = zxb + bl * DIP + hh * HD + p0;
    float yv[32];
    unsigned short zv[32];
#pragma unroll
    for (int k = 0; k < 8; k++) *(float4*)&yv[k * 4] = *(const float4*)(yrow + k * 4);
#pragma unroll
    for (int k = 0; k < 4; k++) *(bf16x8*)&zv[k * 8] = *(const bf16x8*)(zrow + k * 8);

    float yg[32];
    float ss = 0.f;
#pragma unroll
    for (int j = 0; j < 32; j++) {
        const float* hp_ = &Hsn[(p0 + j) * 9 + hh];
        float d = 0.f;
#pragma unroll
        for (int n = 0; n < DSZ; n++) d = fmaf(Cr[n], hp_[n * 576], d);
        float y = yv[j] + d;
        float z = bf2f(zv[j]);
        float g = z / (1.f + __expf(-z));
        yg[j] = y * g;
        ss = fmaf(yg[j], yg[j], ss);
    }
    ss += __shfl_xor(ss, 1);
    ss += __shfl_xor(ss, 2);
    ss += __shfl_xor(ss, 4);
    ss += __shfl_xor(ss, 8);
    float r = rsqrtf(ss * (1.f / DI) + 1e-5f);

    const float* nwp = nw + hh * HD + p0;
    unsigned short* dst = yn_bf + bl * DI + hh * HD + p0;
#pragma unroll
    for (int k = 0; k < 4; k++) {
        bf16x8 o;
#pragma unroll
        for (int j = 0; j < 8; j++) o[j] = (short)f2bf(yg[k * 8 + j] * r * nwp[k * 8 + j]);
        *(bf16x8*)(dst + k * 8) = o;
    }
}

// ---------------- residual add + LayerNorm + mask (+ bf16 copy) ----------------
__global__ __launch_bounds__(256) void k_ln(const float* __restrict__ tmp, float* __restrict__ h,
                                            unsigned short* __restrict__ h_bf,
                                            const float* __restrict__ lnw, const float* __restrict__ lnb,
                                            const float* __restrict__ mask) {
    int bl = blockIdx.x;
    int tid = threadIdx.x;
    size_t idx = (size_t)bl * DM + tid;
    float v = tmp[idx] + h[idx];
    __shared__ float red[4];
    float s = v;
#pragma unroll
    for (int m = 1; m < 64; m <<= 1) s += __shfl_xor(s, m);
    if ((tid & 63) == 0) red[tid >> 6] = s;
    __syncthreads();
    float mu = (red[0] + red[1] + red[2] + red[3]) * (1.f / DM);
    float d = v - mu;
    float q = d * d;
    __syncthreads();
#pragma unroll
    for (int m = 1; m < 64; m <<= 1) q += __shfl_xor(q, m);
    if ((tid & 63) == 0) red[tid >> 6] = q;
    __syncthreads();
    float var = (red[0] + red[1] + red[2] + red[3]) * (1.f / DM);
    float o = (d * rsqrtf(var + 1e-5f) * lnw[tid] + lnb[tid]) * mask[bl];
    h[idx] = o;
    h_bf[idx] = f2bf(o);
}

// ---------------- 2-stage mean-pool + classifier ----------------
__global__ __launch_bounds__(256) void k_pool1(const float* __restrict__ h, float* __restrict__ part) {
    int b = blockIdx.x, g = blockIdx.y, d = threadIdx.x;
    const float* hb = h + ((size_t)b * L_ + g * 128) * DM + d;
    float s = 0.f;
    for (int l = 0; l < 128; l++) s += hb[(size_t)l * DM];
    part[((size_t)b * 16 + g) * DM + d] = s;
}

__global__ __launch_bounds__(256) void k_pool2(const float* __restrict__ part, const float* __restrict__ cw,
                                               const float* __restrict__ cb, float* __restrict__ out) {
    int b = blockIdx.x, tid = threadIdx.x;
    float s = 0.f;
#pragma unroll
    for (int g = 0; g < 16; g++) s += part[((size_t)b * 16 + g) * DM + tid];
    s *= (1.0f / L_);
    float p0 = s * cw[tid];
    float p1 = s * cw[DM + tid];
#pragma unroll
    for (int m = 1; m < 64; m <<= 1) {
        p0 += __shfl_xor(p0, m);
        p1 += __shfl_xor(p1, m);
    }
    __shared__ float r0[4], r1[4];
    if ((tid & 63) == 0) { r0[tid >> 6] = p0; r1[tid >> 6] = p1; }
    __syncthreads();
    if (tid == 0) {
        out[b * 2 + 0] = r0[0] + r0[1] + r0[2] + r0[3] + cb[0];
        out[b * 2 + 1] = r1[0] + r1[1] + r1[2] + r1[3] + cb[1];
    }
}

extern "C" void kernel_launch(void* const* d_in, const int* in_sizes, int n_in,
                              void* d_out, int out_size, void* d_ws, size_t ws_size,
                              hipStream_t stream) {
    const int*   x    = (const int*)d_in[0];
    const float* mask = (const float*)d_in[1];
    const float* emb  = (const float*)d_in[2];
    const float* pos  = (const float*)d_in[3];
    const float* Wi   = (const float*)d_in[4];
    const float* cw   = (const float*)d_in[5];
    const float* cb   = (const float*)d_in[6];
    const float* dtb  = (const float*)d_in[7];
    const float* Alog = (const float*)d_in[8];
    const float* Dp   = (const float*)d_in[9];
    const float* nw   = (const float*)d_in[10];
    const float* Wo   = (const float*)d_in[11];
    const float* lnw  = (const float*)d_in[12];
    const float* lnb  = (const float*)d_in[13];
    const float* clsw = (const float*)d_in[14];
    const float* clsb = (const float*)d_in[15];
    float* out = (float*)d_out;

    float* ws    = (float*)d_ws;
    float* h     = ws;                                   // 16384 x 256
    float* tmp   = h + (size_t)B_ * L_ * DM;             // 16384 x 256
    float* ybuf  = tmp + (size_t)B_ * L_ * DM;           // 16384 x 512 fp32
    float* dtraw = ybuf + (size_t)B_ * L_ * DI;          // 16384 x 8
    float* Sg    = dtraw + (size_t)B_ * L_ * NH;         // 64*32*64*16
    float* Pg    = Sg + (size_t)64 * NC * HD * DSZ;      // 2048
    float* cumL  = Pg + (size_t)64 * NC;                 // 64*32*64
    float* Hg    = cumL + (size_t)64 * NC * Q_;          // 64*32*64*16
    float* Cc    = Hg + (size_t)64 * NC * HD * DSZ;      // 16384 x 16
    float* pool  = Cc + (size_t)B_ * L_ * DSZ;           // 8*16*256
    unsigned short* zxb   = (unsigned short*)(pool + (size_t)B_ * 16 * DM);  // 16384 x 1064
    unsigned short* h_bf  = zxb + (size_t)B_ * L_ * DIP;
    unsigned short* yn_bf = h_bf + (size_t)B_ * L_ * DM;
    unsigned short* Wi_bf = yn_bf + (size_t)B_ * L_ * DI;
    unsigned short* Wo_bf = Wi_bf + (size_t)4 * DIP * DM;

    k_f2bf<<<(4 * DIP * DM / 4 + 255) / 256, 256, 0, stream>>>(Wi, Wi_bf, 4 * DIP * DM / 4);
    k_f2bf<<<(4 * DM * DI / 4 + 255) / 256, 256, 0, stream>>>(Wo, Wo_bf, 4 * DM * DI / 4);

    k_embed<<<(B_ * L_ * DM + 255) / 256, 256, 0, stream>>>(x, mask, emb, pos, h, h_bf);

    for (int i = 0; i < 4; i++) {
        // zxbcdt = h @ Wi^T -> bf16 zxb (+ fp32 dtraw cols)
        k_gemm<1><<<dim3(B_ * L_ / 128, (DIP + 127) / 128), 256, 0, stream>>>(
            h_bf, DM, Wi_bf + (size_t)i * DIP * DM, DM, DIP, zxb, DIP, DM, dtraw);
        // fused conv+silu+dt + intra-chunk scan (MFMA)
        k_scan1c<<<dim3(64, NC), 256, 0, stream>>>(
            zxb, dtraw, cw + (size_t)i * CD * 4, cb + i * CD, dtb + i * NH, Alog + i * NH,
            Dp + i * NH, ybuf, Sg, Pg, cumL, Cc);
        k_scan2<<<64, 256, 0, stream>>>(Sg, Pg, Hg);
        // fused cross-chunk + gated RMSNorm -> bf16 yn
        k_scan3g<<<dim3(B_, 128), 256, 0, stream>>>(ybuf, zxb, Hg, cumL, Cc, nw + (size_t)i * DI, yn_bf);
        // out = yn @ Wo^T -> fp32 tmp
        k_gemm<0><<<dim3(B_ * L_ / 128, DM / 128), 256, 0, stream>>>(
            yn_bf, DI, Wo_bf + (size_t)i * DM * DI, DI, DM, tmp, DM, DI, nullptr);
        k_ln<<<B_ * L_, 256, 0, stream>>>(tmp, h, h_bf, lnw, lnb, mask);
    }

    k_pool1<<<dim3(B_, 16), 256, 0, stream>>>(h, pool);
    k_pool2<<<B_, 256, 0, stream>>>(pool, clsw, clsb, out);
}

// Round 9
// 442.812 us; speedup vs baseline: 1.6003x; 1.1787x over previous
//
#include <hip/hip_runtime.h>
#include <hip/hip_bf16.h>
#include <math.h>

#define B_ 8
#define L_ 2048
#define DM 256
#define DIP 1064
#define DI 512
#define CD 544
#define DSZ 16
#define NH 8
#define HD 64
#define Q_ 64
#define NC 32

typedef __attribute__((ext_vector_type(8))) short bf16x8;
typedef __attribute__((ext_vector_type(4))) float f32x4;

__device__ inline unsigned short f2bf(float f) {
    __hip_bfloat16 h = __float2bfloat16(f);
    return *(unsigned short*)&h;
}
__device__ inline float bf2f(unsigned short u) {
    unsigned int x = ((unsigned int)u) << 16;
    return __uint_as_float(x);
}

// ---------------- fp32 -> bf16 bulk convert ----------------
__global__ __launch_bounds__(256) void k_f2bf(const float* __restrict__ in, unsigned short* __restrict__ out, int n4) {
    int i = blockIdx.x * 256 + threadIdx.x;
    if (i >= n4) return;
    float4 v = *(const float4*)(in + (size_t)i * 4);
    ushort4 o;
    o.x = f2bf(v.x); o.y = f2bf(v.y); o.z = f2bf(v.z); o.w = f2bf(v.w);
    *(ushort4*)(out + (size_t)i * 4) = o;
}

// ---------------- embed ----------------
__global__ __launch_bounds__(256) void k_embed(const int* __restrict__ x, const float* __restrict__ mask,
                                               const float* __restrict__ emb, const float* __restrict__ pos,
                                               float* __restrict__ h, unsigned short* __restrict__ h_bf) {
    int i = blockIdx.x * 256 + threadIdx.x;
    if (i >= B_ * L_ * DM) return;
    int d = i % DM;
    int bl = i / DM;
    int l = bl % L_;
    int tok = x[bl];
    float v = (emb[tok * DM + d] + pos[l * DM + d]) * mask[bl];
    h[i] = v;
    h_bf[i] = f2bf(v);
}

// ---------------- bf16 MFMA NT GEMM (128x128 tile, BK=32, global_load_lds) ----------------
// OUTMODE 0: fp32 C.  OUTMODE 1: bf16 C + fp32 dtraw side-buffer for cols >= DI+CD.
template <int OUTMODE>
__global__ __launch_bounds__(256) void k_gemm(const unsigned short* __restrict__ A, int lda,
                                              const unsigned short* __restrict__ Bw, int ldb, int N,
                                              void* __restrict__ Cout, int ldc, int K,
                                              float* __restrict__ dtraw) {
    __shared__ unsigned short Al[2][128 * 32];
    __shared__ unsigned short Bl[2][128 * 32];
    int tid = threadIdx.x;
    int l = tid & 63;
    int w = tid >> 6, wr = w >> 1, wc = w & 1;
    int m0 = blockIdx.x * 128, n0 = blockIdx.y * 128;

    f32x4 zero = {0.f, 0.f, 0.f, 0.f};
    f32x4 acc[4][4];
#pragma unroll
    for (int i = 0; i < 4; i++)
#pragma unroll
        for (int j = 0; j < 4; j++) acc[i][j] = zero;

    int lr = l & 15, kq = l >> 4;
    int aoff = (wr * 64 + lr) * 32 + kq * 8;
    int boff = (wc * 64 + lr) * 32 + kq * 8;

    auto stage = [&](int ks, int buf) {
        int k0 = ks * 32;
#pragma unroll
        for (int q = 0; q < 2; q++) {
            int c = tid + q * 256;
            int row = c >> 2, cc = (c & 3) * 8;
            const unsigned short* ga = A + (size_t)(m0 + row) * lda + k0 + cc;
            __builtin_amdgcn_global_load_lds((const __attribute__((address_space(1))) void*)ga,
                                             (__attribute__((address_space(3))) void*)(&Al[buf][c * 8]), 16, 0, 0);
            int rowb = n0 + row;
            if (rowb > N - 1) rowb = N - 1;
            const unsigned short* gb = Bw + (size_t)rowb * ldb + k0 + cc;
            __builtin_amdgcn_global_load_lds((const __attribute__((address_space(1))) void*)gb,
                                             (__attribute__((address_space(3))) void*)(&Bl[buf][c * 8]), 16, 0, 0);
        }
    };

    stage(0, 0);
    int ksteps = K / 32;
    for (int s = 0; s < ksteps; s++) {
        int buf = s & 1;
        __syncthreads();
        if (s + 1 < ksteps) stage(s + 1, buf ^ 1);
        bf16x8 a[4], b[4];
#pragma unroll
        for (int i = 0; i < 4; i++) a[i] = *(const bf16x8*)&Al[buf][aoff + i * 512];
#pragma unroll
        for (int j = 0; j < 4; j++) b[j] = *(const bf16x8*)&Bl[buf][boff + j * 512];
#pragma unroll
        for (int i = 0; i < 4; i++)
#pragma unroll
            for (int j = 0; j < 4; j++)
                acc[i][j] = __builtin_amdgcn_mfma_f32_16x16x32_bf16(a[i], b[j], acc[i][j], 0, 0, 0);
    }

#pragma unroll
    for (int i = 0; i < 4; i++) {
        int m = m0 + wr * 64 + i * 16 + kq * 4;
#pragma unroll
        for (int j = 0; j < 4; j++) {
            int n = n0 + wc * 64 + j * 16 + lr;
            if (n < N) {
                if (OUTMODE == 0) {
                    float* C = (float*)Cout;
#pragma unroll
                    for (int r = 0; r < 4; r++)
                        C[(size_t)(m + r) * ldc + n] = acc[i][j][r];
                } else {
                    unsigned short* C = (unsigned short*)Cout;
#pragma unroll
                    for (int r = 0; r < 4; r++)
                        C[(size_t)(m + r) * ldc + n] = f2bf(acc[i][j][r]);
                    if (n >= DI + CD) {
#pragma unroll
                        for (int r = 0; r < 4; r++)
                            dtraw[(size_t)(m + r) * NH + (n - (DI + CD))] = acc[i][j][r];
                    }
                }
            }
        }
    }
}

// ---------------- fused conv+silu+dt + chunked scan stage 1 (MFMA) ----------------
// X-conv computed with phase-2 thread mapping; D*x kept in registers (fp32 exact).
// LDS ~33 KB -> 4 blocks/CU.
__global__ __launch_bounds__(256) void k_scan1c(const unsigned short* __restrict__ zxb,
                                                const float* __restrict__ dtraw,
                                                const float* __restrict__ cw, const float* __restrict__ cb,
                                                const float* __restrict__ dtb, const float* __restrict__ Alog,
                                                const float* __restrict__ Dp,
                                                float* __restrict__ ybuf, float* __restrict__ Sg,
                                                float* __restrict__ Pg, float* __restrict__ cumLg,
                                                float* __restrict__ Cc) {
    int bh = blockIdx.x, c = blockIdx.y;
    int b = bh >> 3, h = bh & 7;
    int tid = threadIdx.x;
    int t0 = c * Q_;
    int w = tid >> 6, l = tid & 63;
    int lr = l & 15, kq = l >> 4;

    __shared__ __align__(16) unsigned short Zl[67 * 96];     // 12.6 KB staged zx; aliased by Mbf after conv
    __shared__ __align__(16) unsigned short Xt[Q_ * 72];     // 9.2 KB  X^T [p][s]
    __shared__ __align__(16) unsigned short Cbf[Q_ * 32];    // 4 KB
    __shared__ __align__(16) unsigned short Bbf[Q_ * 32];    // 4 KB
    __shared__ __align__(16) unsigned short Btw[DSZ * 72];   // 2.25 KB (dedicated)
    __shared__ float Lc[Q_], dts[Q_], coefS[Q_];
    unsigned short* Mbf = Zl;            // 64*64 shorts (8 KB), Zl dead after conv barrier

    float Dval = Dp[h];

    // ---- stage Zl: rows t0-3..t0+63; cols 0..63 = X head slice, 64..95 = B|C ----
    for (int idx = tid; idx < 67 * 12; idx += 256) {
        int rr = idx / 12, seg = idx - rr * 12;
        int lg = t0 - 3 + rr;
        bf16x8 v;
        if (lg >= 0) {
            const unsigned short* src = zxb + (size_t)(b * L_ + lg) * DIP +
                                        (seg < 8 ? (DI + h * HD + seg * 8) : (1024 + (seg - 8) * 8));
            v = *(const bf16x8*)src;
        } else {
#pragma unroll
            for (int j = 0; j < 8; j++) v[j] = 0;
        }
        int col = (seg < 8) ? seg * 8 : (64 + (seg - 8) * 8);
        *(bf16x8*)&Zl[rr * 96 + col] = v;
    }
    // ---- zero-fill Cbf/Bbf K-pad ----
    {
        bf16x8 z8;
#pragma unroll
        for (int j = 0; j < 8; j++) z8[j] = 0;
        *(bf16x8*)&Cbf[tid * 8] = z8;
        *(bf16x8*)&Bbf[tid * 8] = z8;
    }
    // ---- dt / ldA / log-cumsum (wave 0) ----
    if (tid < 64) {
        float raw = dtraw[(size_t)(b * L_ + t0 + tid) * NH + h] + dtb[h];
        float dtv = (raw > 20.f) ? raw : log1pf(__expf(raw));
        float v = -__expf(Alog[h]) * dtv;
#pragma unroll
        for (int off = 1; off < 64; off <<= 1) {
            float u = __shfl_up(v, off);
            if (tid >= off) v += u;
        }
        dts[tid] = dtv;
        Lc[tid] = v;
        float lend = __shfl(v, 63);
        coefS[tid] = __expf(lend - v) * dtv;
        cumLg[(size_t)(bh * NC + c) * Q_ + tid] = v;
        if (tid == 63) Pg[bh * NC + c] = __expf(v);
    }
    __syncthreads();

    // ---- X-conv (phase-2 mapping): 16 values/thread, fp32 in regs + bf16 Xt ----
    float xreg[4][4];
#pragma unroll
    for (int pt = 0; pt < 4; pt++) {
#pragma unroll
        for (int r = 0; r < 4; r++) {
            int t = w * 16 + kq * 4 + r;
            int p = pt * 16 + lr;
            int cc = h * HD + p;
            float acc = cb[cc];
#pragma unroll
            for (int k = 0; k < 4; k++)
                acc = fmaf(bf2f(Zl[(t + k) * 96 + p]), cw[cc * 4 + k], acc);
            float s = acc / (1.f + __expf(-acc));
            xreg[pt][r] = s;
            Xt[p * 72 + t] = f2bf(s);
        }
    }
    // ---- B/C conv: 2048 items, 8/thread ----
    for (int idx = tid; idx < Q_ * 32; idx += 256) {
        int t = idx >> 5, n32 = idx & 31;
        int cc = DI + n32;
        float acc = cb[cc];
#pragma unroll
        for (int k = 0; k < 4; k++)
            acc = fmaf(bf2f(Zl[(t + k) * 96 + 64 + n32]), cw[cc * 4 + k], acc);
        float s = acc / (1.f + __expf(-acc));
        if (n32 < 16) {
            int n = n32;
            Bbf[t * 32 + (((n >> 3) ^ (t & 3)) * 8) + (n & 7)] = f2bf(dts[t] * s);
            Btw[n * 72 + t] = f2bf(coefS[t] * s);
        } else {
            int n = n32 - 16;
            Cbf[t * 32 + (((n >> 3) ^ (t & 3)) * 8) + (n & 7)] = f2bf(s);
            if (h == 0) Cc[((size_t)(b * L_ + t0 + t)) * DSZ + n] = s;
        }
    }
    __syncthreads();

    f32x4 zero = {0.f, 0.f, 0.f, 0.f};

    // phase 1: CB tiles (wave w owns t-tile w), K=32 (zero-padded)
    f32x4 cbt[4];
    {
        bf16x8 af = *(const bf16x8*)&Cbf[(w * 16 + lr) * 32 + ((kq ^ (lr & 3)) * 8)];
#pragma unroll
        for (int st = 0; st < 4; st++) {
            bf16x8 bf = *(const bf16x8*)&Bbf[(st * 16 + lr) * 32 + ((kq ^ (lr & 3)) * 8)];
            cbt[st] = __builtin_amdgcn_mfma_f32_16x16x32_bf16(af, bf, zero, 0, 0, 0);
        }
    }
    // mask + decay -> Mbf (aliases Zl, dead now)
#pragma unroll
    for (int st = 0; st < 4; st++) {
#pragma unroll
        for (int r = 0; r < 4; r++) {
            int t = w * 16 + kq * 4 + r;
            int s = st * 16 + lr;
            float m = (s <= t) ? __expf(Lc[t] - Lc[s]) * cbt[st][r] : 0.f;
            Mbf[t * 64 + (((s >> 3) ^ (t & 7)) * 8) + (s & 7)] = f2bf(m);
        }
    }
    __syncthreads();

    // phase 2: Y = M * X + D*x (fp32 register epilogue) -> fp32 ybuf
    {
        float* base_y = ybuf + ((size_t)b * L_ + t0) * DI + h * HD;
        f32x4 acc[4];
#pragma unroll
        for (int pt = 0; pt < 4; pt++) acc[pt] = zero;
#pragma unroll
        for (int ks = 0; ks < 2; ks++) {
            bf16x8 af = *(const bf16x8*)&Mbf[(w * 16 + lr) * 64 + (((ks * 4 + kq) ^ (lr & 7)) * 8)];
#pragma unroll
            for (int pt = 0; pt < 4; pt++) {
                bf16x8 bf = *(const bf16x8*)&Xt[(pt * 16 + lr) * 72 + ks * 32 + kq * 8];
                acc[pt] = __builtin_amdgcn_mfma_f32_16x16x32_bf16(af, bf, acc[pt], 0, 0, 0);
            }
        }
#pragma unroll
        for (int pt = 0; pt < 4; pt++) {
#pragma unroll
            for (int r = 0; r < 4; r++) {
                int t = w * 16 + kq * 4 + r;
                int p = pt * 16 + lr;
                base_y[(size_t)t * DI + p] = acc[pt][r] + Dval * xreg[pt][r];
            }
        }
    }

    // phase 3: chunk state S = X^T * (coef*B)
    {
        f32x4 sacc = zero;
#pragma unroll
        for (int ks = 0; ks < 2; ks++) {
            bf16x8 af = *(const bf16x8*)&Xt[(w * 16 + lr) * 72 + ks * 32 + kq * 8];
            bf16x8 bf = *(const bf16x8*)&Btw[lr * 72 + ks * 32 + kq * 8];
            sacc = __builtin_amdgcn_mfma_f32_16x16x32_bf16(af, bf, sacc, 0, 0, 0);
        }
#pragma unroll
        for (int r = 0; r < 4; r++) {
            int p = w * 16 + kq * 4 + r;
            Sg[((size_t)(bh * NC + c) * HD + p) * DSZ + lr] = sacc[r];
        }
    }
}

// ---------------- chunked scan stage 2 ----------------
__global__ __launch_bounds__(256) void k_scan2(const float* __restrict__ Sg, const float* __restrict__ Pg,
                                               float* __restrict__ Hg) {
    int bh = blockIdx.x;
    int tid = threadIdx.x;
    int p = tid >> 2, n0 = (tid & 3) * 4;
    float4 H = make_float4(0.f, 0.f, 0.f, 0.f);
    for (int c = 0; c < NC; c++) {
        size_t base = ((size_t)(bh * NC + c) * HD + p) * DSZ + n0;
        float P = Pg[bh * NC + c];
        float4 S = *(const float4*)(Sg + base);
        *(float4*)(Hg + base) = H;
        H.x = fmaf(P, H.x, S.x);
        H.y = fmaf(P, H.y, S.y);
        H.z = fmaf(P, H.z, S.z);
        H.w = fmaf(P, H.w, S.w);
    }
}

// ---------------- fused scan stage 3 + gated RMSNorm -> bf16 yn ----------------
__global__ __launch_bounds__(256) void k_scan3g(const float* __restrict__ ybuf,
                                                const unsigned short* __restrict__ zxb,
                                                const float* __restrict__ Hg, const float* __restrict__ cumLg,
                                                const float* __restrict__ Cc, const float* __restrict__ nw,
                                                unsigned short* __restrict__ yn_bf) {
    int b = blockIdx.x, by = blockIdx.y;
    int c64 = by >> 2, tl0 = (by & 3) * 16;
    int t0 = by * 16;
    int tid = threadIdx.x;
    __shared__ float Hsn[DSZ * 576];   // n*576 + p*9 + hh  (36 KB)
    __shared__ float Lq[NH][16];

    {
        int p = tid & 63, hp = tid >> 6;
#pragma unroll
        for (int ho = 0; ho < 2; ho++) {
            int hh = hp * 2 + ho;
            const float* src = Hg + (((size_t)(b * NH + hh) * NC + c64) * HD + p) * DSZ;
            float* dst = &Hsn[p * 9 + hh];
#pragma unroll
            for (int nq = 0; nq < 4; nq++) {
                float4 v = *(const float4*)(src + nq * 4);
                dst[(nq * 4 + 0) * 576] = v.x;
                dst[(nq * 4 + 1) * 576] = v.y;
                dst[(nq * 4 + 2) * 576] = v.z;
                dst[(nq * 4 + 3) * 576] = v.w;
            }
        }
    }
    if (tid < 128) {
        int hh = tid >> 4, t = tid & 15;
        Lq[hh][t] = cumLg[((size_t)(b * NH + hh) * NC + c64) * Q_ + tl0 + t];
    }
    __syncthreads();

    int t = tid >> 4, q = tid & 15;
    int hh = q >> 1, p0 = (q & 1) * 32;
    size_t bl = (size_t)b * L_ + t0 + t;
    float ef = __expf(Lq[hh][t]);

    float Cr[16];
#pragma unroll
    for (int k = 0; k < 4; k++) {
        float4 v = *(const float4*)(Cc + bl * DSZ + k * 4);
        Cr[4 * k + 0] = ef * v.x;
        Cr[4 * k + 1] = ef * v.y;
        Cr[4 * k + 2] = ef * v.z;
        Cr[4 * k + 3] = ef * v.w;
    }

    const float* yrow = ybuf + bl * DI + hh * HD + p0;
    const unsigned short* zrow = zxb + bl * DIP + hh * HD + p0;
    float yv[32];
    unsigned short zv[32];
#pragma unroll
    for (int k = 0; k < 8; k++) *(float4*)&yv[k * 4] = *(const float4*)(yrow + k * 4);
#pragma unroll
    for (int k = 0; k < 4; k++) *(bf16x8*)&zv[k * 8] = *(const bf16x8*)(zrow + k * 8);

    float yg[32];
    float ss = 0.f;
#pragma unroll
    for (int j = 0; j < 32; j++) {
        const float* hp_ = &Hsn[(p0 + j) * 9 + hh];
        float d = 0.f;
#pragma unroll
        for (int n = 0; n < DSZ; n++) d = fmaf(Cr[n], hp_[n * 576], d);
        float y = yv[j] + d;
        float z = bf2f(zv[j]);
        float g = z / (1.f + __expf(-z));
        yg[j] = y * g;
        ss = fmaf(yg[j], yg[j], ss);
    }
    ss += __shfl_xor(ss, 1);
    ss += __shfl_xor(ss, 2);
    ss += __shfl_xor(ss, 4);
    ss += __shfl_xor(ss, 8);
    float r = rsqrtf(ss * (1.f / DI) + 1e-5f);

    const float* nwp = nw + hh * HD + p0;
    unsigned short* dst = yn_bf + bl * DI + hh * HD + p0;
#pragma unroll
    for (int k = 0; k < 4; k++) {
        bf16x8 o;
#pragma unroll
        for (int j = 0; j < 8; j++) o[j] = (short)f2bf(yg[k * 8 + j] * r * nwp[k * 8 + j]);
        *(bf16x8*)(dst + k * 8) = o;
    }
}

// ---------------- residual add + LayerNorm + mask (wave-per-row, no barriers) ----------------
__global__ __launch_bounds__(256) void k_ln(const float* __restrict__ tmp, float* __restrict__ h,
                                            unsigned short* __restrict__ h_bf,
                                            const float* __restrict__ lnw, const float* __restrict__ lnb,
                                            const float* __restrict__ mask) {
    int row = blockIdx.x * 4 + (threadIdx.x >> 6);
    int lane = threadIdx.x & 63;
    size_t base = (size_t)row * DM + lane * 4;
    float4 tv = *(const float4*)(tmp + base);
    float4 hv = *(const float4*)(h + base);
    float v[4] = {tv.x + hv.x, tv.y + hv.y, tv.z + hv.z, tv.w + hv.w};
    float s = v[0] + v[1] + v[2] + v[3];
#pragma unroll
    for (int m = 1; m < 64; m <<= 1) s += __shfl_xor(s, m);
    float mu = s * (1.f / DM);
    float q = 0.f;
#pragma unroll
    for (int j = 0; j < 4; j++) {
        float d = v[j] - mu;
        q = fmaf(d, d, q);
    }
#pragma unroll
    for (int m = 1; m < 64; m <<= 1) q += __shfl_xor(q, m);
    float rs = rsqrtf(q * (1.f / DM) + 1e-5f);
    float mk = mask[row];
    float4 wv = *(const float4*)(lnw + lane * 4);
    float4 bv = *(const float4*)(lnb + lane * 4);
    float o[4];
    o[0] = ((v[0] - mu) * rs * wv.x + bv.x) * mk;
    o[1] = ((v[1] - mu) * rs * wv.y + bv.y) * mk;
    o[2] = ((v[2] - mu) * rs * wv.z + bv.z) * mk;
    o[3] = ((v[3] - mu) * rs * wv.w + bv.w) * mk;
    *(float4*)(h + base) = make_float4(o[0], o[1], o[2], o[3]);
    ushort4 ob;
    ob.x = f2bf(o[0]); ob.y = f2bf(o[1]); ob.z = f2bf(o[2]); ob.w = f2bf(o[3]);
    *(ushort4*)(h_bf + base) = ob;
}

// ---------------- 2-stage mean-pool + classifier ----------------
__global__ __launch_bounds__(256) void k_pool1(const float* __restrict__ h, float* __restrict__ part) {
    int b = blockIdx.x, g = blockIdx.y, d = threadIdx.x;
    const float* hb = h + ((size_t)b * L_ + g * 128) * DM + d;
    float s = 0.f;
    for (int l = 0; l < 128; l++) s += hb[(size_t)l * DM];
    part[((size_t)b * 16 + g) * DM + d] = s;
}

__global__ __launch_bounds__(256) void k_pool2(const float* __restrict__ part, const float* __restrict__ cw,
                                               const float* __restrict__ cb, float* __restrict__ out) {
    int b = blockIdx.x, tid = threadIdx.x;
    float s = 0.f;
#pragma unroll
    for (int g = 0; g < 16; g++) s += part[((size_t)b * 16 + g) * DM + tid];
    s *= (1.0f / L_);
    float p0 = s * cw[tid];
    float p1 = s * cw[DM + tid];
#pragma unroll
    for (int m = 1; m < 64; m <<= 1) {
        p0 += __shfl_xor(p0, m);
        p1 += __shfl_xor(p1, m);
    }
    __shared__ float r0[4], r1[4];
    if ((tid & 63) == 0) { r0[tid >> 6] = p0; r1[tid >> 6] = p1; }
    __syncthreads();
    if (tid == 0) {
        out[b * 2 + 0] = r0[0] + r0[1] + r0[2] + r0[3] + cb[0];
        out[b * 2 + 1] = r1[0] + r1[1] + r1[2] + r1[3] + cb[1];
    }
}

extern "C" void kernel_launch(void* const* d_in, const int* in_sizes, int n_in,
                              void* d_out, int out_size, void* d_ws, size_t ws_size,
                              hipStream_t stream) {
    const int*   x    = (const int*)d_in[0];
    const float* mask = (const float*)d_in[1];
    const float* emb  = (const float*)d_in[2];
    const float* pos  = (const float*)d_in[3];
    const float* Wi   = (const float*)d_in[4];
    const float* cw   = (const float*)d_in[5];
    const float* cb   = (const float*)d_in[6];
    const float* dtb  = (const float*)d_in[7];
    const float* Alog = (const float*)d_in[8];
    const float* Dp   = (const float*)d_in[9];
    const float* nw   = (const float*)d_in[10];
    const float* Wo   = (const float*)d_in[11];
    const float* lnw  = (const float*)d_in[12];
    const float* lnb  = (const float*)d_in[13];
    const float* clsw = (const float*)d_in[14];
    const float* clsb = (const float*)d_in[15];
    float* out = (float*)d_out;

    float* ws    = (float*)d_ws;
    float* h     = ws;                                   // 16384 x 256
    float* tmp   = h + (size_t)B_ * L_ * DM;             // 16384 x 256
    float* ybuf  = tmp + (size_t)B_ * L_ * DM;           // 16384 x 512 fp32
    float* dtraw = ybuf + (size_t)B_ * L_ * DI;          // 16384 x 8
    float* Sg    = dtraw + (size_t)B_ * L_ * NH;         // 64*32*64*16
    float* Pg    = Sg + (size_t)64 * NC * HD * DSZ;      // 2048
    float* cumL  = Pg + (size_t)64 * NC;                 // 64*32*64
    float* Hg    = cumL + (size_t)64 * NC * Q_;          // 64*32*64*16
    float* Cc    = Hg + (size_t)64 * NC * HD * DSZ;      // 16384 x 16
    float* pool  = Cc + (size_t)B_ * L_ * DSZ;           // 8*16*256
    unsigned short* zxb   = (unsigned short*)(pool + (size_t)B_ * 16 * DM);  // 16384 x 1064
    unsigned short* h_bf  = zxb + (size_t)B_ * L_ * DIP;
    unsigned short* yn_bf = h_bf + (size_t)B_ * L_ * DM;
    unsigned short* Wi_bf = yn_bf + (size_t)B_ * L_ * DI;
    unsigned short* Wo_bf = Wi_bf + (size_t)4 * DIP * DM;

    k_f2bf<<<(4 * DIP * DM / 4 + 255) / 256, 256, 0, stream>>>(Wi, Wi_bf, 4 * DIP * DM / 4);
    k_f2bf<<<(4 * DM * DI / 4 + 255) / 256, 256, 0, stream>>>(Wo, Wo_bf, 4 * DM * DI / 4);

    k_embed<<<(B_ * L_ * DM + 255) / 256, 256, 0, stream>>>(x, mask, emb, pos, h, h_bf);

    for (int i = 0; i < 4; i++) {
        // zxbcdt = h @ Wi^T -> bf16 zxb (+ fp32 dtraw cols)
        k_gemm<1><<<dim3(B_ * L_ / 128, (DIP + 127) / 128), 256, 0, stream>>>(
            h_bf, DM, Wi_bf + (size_t)i * DIP * DM, DM, DIP, zxb, DIP, DM, dtraw);
        // fused conv+silu+dt + intra-chunk scan (MFMA)
        k_scan1c<<<dim3(64, NC), 256, 0, stream>>>(
            zxb, dtraw, cw + (size_t)i * CD * 4, cb + i * CD, dtb + i * NH, Alog + i * NH,
            Dp + i * NH, ybuf, Sg, Pg, cumL, Cc);
        k_scan2<<<64, 256, 0, stream>>>(Sg, Pg, Hg);
        // fused cross-chunk + gated RMSNorm -> bf16 yn
        k_scan3g<<<dim3(B_, 128), 256, 0, stream>>>(ybuf, zxb, Hg, cumL, Cc, nw + (size_t)i * DI, yn_bf);
        // out = yn @ Wo^T -> fp32 tmp
        k_gemm<0><<<dim3(B_ * L_ / 128, DM / 128), 256, 0, stream>>>(
            yn_bf, DI, Wo_bf + (size_t)i * DM * DI, DI, DM, tmp, DM, DI, nullptr);
        k_ln<<<B_ * L_ / 4, 256, 0, stream>>>(tmp, h, h_bf, lnw, lnb, mask);
    }

    k_pool1<<<dim3(B_, 16), 256, 0, stream>>>(h, pool);
    k_pool2<<<B_, 256, 0, stream>>>(pool, clsw, clsb, out);
}

// Round 10
// 418.087 us; speedup vs baseline: 1.6950x; 1.0591x over previous
//
#include <hip/hip_runtime.h>
#include <hip/hip_bf16.h>
#include <math.h>

#define B_ 8
#define L_ 2048
#define DM 256
#define DIP 1064
#define DI 512
#define CD 544
#define DSZ 16
#define NH 8
#define HD 64
#define Q_ 64
#define NC 32

typedef __attribute__((ext_vector_type(8))) short bf16x8;
typedef __attribute__((ext_vector_type(4))) float f32x4;

__device__ inline unsigned short f2bf(float f) {
    __hip_bfloat16 h = __float2bfloat16(f);
    return *(unsigned short*)&h;
}
__device__ inline float bf2f(unsigned short u) {
    unsigned int x = ((unsigned int)u) << 16;
    return __uint_as_float(x);
}
__device__ inline float fast_sig(float x) {            // ~2e-7 rel err, consumed at bf16
    return __builtin_amdgcn_rcpf(1.f + __expf(-x));
}

// ---------------- fp32 -> bf16 bulk convert ----------------
__global__ __launch_bounds__(256) void k_f2bf(const float* __restrict__ in, unsigned short* __restrict__ out, int n4) {
    int i = blockIdx.x * 256 + threadIdx.x;
    if (i >= n4) return;
    float4 v = *(const float4*)(in + (size_t)i * 4);
    ushort4 o;
    o.x = f2bf(v.x); o.y = f2bf(v.y); o.z = f2bf(v.z); o.w = f2bf(v.w);
    *(ushort4*)(out + (size_t)i * 4) = o;
}

// ---------------- embed ----------------
__global__ __launch_bounds__(256) void k_embed(const int* __restrict__ x, const float* __restrict__ mask,
                                               const float* __restrict__ emb, const float* __restrict__ pos,
                                               float* __restrict__ h, unsigned short* __restrict__ h_bf) {
    int i = blockIdx.x * 256 + threadIdx.x;
    if (i >= B_ * L_ * DM) return;
    int d = i % DM;
    int bl = i / DM;
    int l = bl % L_;
    int tok = x[bl];
    float v = (emb[tok * DM + d] + pos[l * DM + d]) * mask[bl];
    h[i] = v;
    h_bf[i] = f2bf(v);
}

// ---------------- bf16 MFMA NT GEMM (128x128 tile, BK=32, global_load_lds) ----------------
// OUTMODE 0: fp32 C.  OUTMODE 1: bf16 C + fp32 dtraw for cols >= DI+CD.  OUTMODE 2: bf16 C.
template <int OUTMODE>
__global__ __launch_bounds__(256) void k_gemm(const unsigned short* __restrict__ A, int lda,
                                              const unsigned short* __restrict__ Bw, int ldb, int N,
                                              void* __restrict__ Cout, int ldc, int K,
                                              float* __restrict__ dtraw) {
    __shared__ unsigned short Al[2][128 * 32];
    __shared__ unsigned short Bl[2][128 * 32];
    int tid = threadIdx.x;
    int l = tid & 63;
    int w = tid >> 6, wr = w >> 1, wc = w & 1;
    int m0 = blockIdx.x * 128, n0 = blockIdx.y * 128;

    f32x4 zero = {0.f, 0.f, 0.f, 0.f};
    f32x4 acc[4][4];
#pragma unroll
    for (int i = 0; i < 4; i++)
#pragma unroll
        for (int j = 0; j < 4; j++) acc[i][j] = zero;

    int lr = l & 15, kq = l >> 4;
    int aoff = (wr * 64 + lr) * 32 + kq * 8;
    int boff = (wc * 64 + lr) * 32 + kq * 8;

    auto stage = [&](int ks, int buf) {
        int k0 = ks * 32;
#pragma unroll
        for (int q = 0; q < 2; q++) {
            int c = tid + q * 256;
            int row = c >> 2, cc = (c & 3) * 8;
            const unsigned short* ga = A + (size_t)(m0 + row) * lda + k0 + cc;
            __builtin_amdgcn_global_load_lds((const __attribute__((address_space(1))) void*)ga,
                                             (__attribute__((address_space(3))) void*)(&Al[buf][c * 8]), 16, 0, 0);
            int rowb = n0 + row;
            if (rowb > N - 1) rowb = N - 1;
            const unsigned short* gb = Bw + (size_t)rowb * ldb + k0 + cc;
            __builtin_amdgcn_global_load_lds((const __attribute__((address_space(1))) void*)gb,
                                             (__attribute__((address_space(3))) void*)(&Bl[buf][c * 8]), 16, 0, 0);
        }
    };

    stage(0, 0);
    int ksteps = K / 32;
    for (int s = 0; s < ksteps; s++) {
        int buf = s & 1;
        __syncthreads();
        if (s + 1 < ksteps) stage(s + 1, buf ^ 1);
        bf16x8 a[4], b[4];
#pragma unroll
        for (int i = 0; i < 4; i++) a[i] = *(const bf16x8*)&Al[buf][aoff + i * 512];
#pragma unroll
        for (int j = 0; j < 4; j++) b[j] = *(const bf16x8*)&Bl[buf][boff + j * 512];
#pragma unroll
        for (int i = 0; i < 4; i++)
#pragma unroll
            for (int j = 0; j < 4; j++)
                acc[i][j] = __builtin_amdgcn_mfma_f32_16x16x32_bf16(a[i], b[j], acc[i][j], 0, 0, 0);
    }

#pragma unroll
    for (int i = 0; i < 4; i++) {
        int m = m0 + wr * 64 + i * 16 + kq * 4;
#pragma unroll
        for (int j = 0; j < 4; j++) {
            int n = n0 + wc * 64 + j * 16 + lr;
            if (n < N) {
                if (OUTMODE == 0) {
                    float* C = (float*)Cout;
#pragma unroll
                    for (int r = 0; r < 4; r++)
                        C[(size_t)(m + r) * ldc + n] = acc[i][j][r];
                } else {
                    unsigned short* C = (unsigned short*)Cout;
#pragma unroll
                    for (int r = 0; r < 4; r++)
                        C[(size_t)(m + r) * ldc + n] = f2bf(acc[i][j][r]);
                    if (OUTMODE == 1 && n >= DI + CD) {
#pragma unroll
                        for (int r = 0; r < 4; r++)
                            dtraw[(size_t)(m + r) * NH + (n - (DI + CD))] = acc[i][j][r];
                    }
                }
            }
        }
    }
}

// ---------------- fused conv+silu+dt + chunked scan stage 1 (MFMA) ----------------
__global__ __launch_bounds__(256) void k_scan1c(const unsigned short* __restrict__ zxb,
                                                const float* __restrict__ dtraw,
                                                const float* __restrict__ cw, const float* __restrict__ cb,
                                                const float* __restrict__ dtb, const float* __restrict__ Alog,
                                                const float* __restrict__ Dp,
                                                unsigned short* __restrict__ ybuf, float* __restrict__ Sg,
                                                float* __restrict__ Pg, float* __restrict__ cumLg,
                                                float* __restrict__ Cc) {
    int bh = blockIdx.x, c = blockIdx.y;
    int b = bh >> 3, h = bh & 7;
    int tid = threadIdx.x;
    int t0 = c * Q_;
    int w = tid >> 6, l = tid & 63;
    int lr = l & 15, kq = l >> 4;

    __shared__ __align__(16) unsigned short Zl[67 * 96];     // staged zx; aliased by Mbf after conv
    __shared__ __align__(16) unsigned short Xt[Q_ * 72];
    __shared__ __align__(16) unsigned short Cbf[Q_ * 32];
    __shared__ __align__(16) unsigned short Bbf[Q_ * 32];
    __shared__ __align__(16) unsigned short Btw[DSZ * 72];
    __shared__ float Lc[Q_], dts[Q_], coefS[Q_];
    unsigned short* Mbf = Zl;

    float Dval = Dp[h];

    // ---- stage Zl ----
    for (int idx = tid; idx < 67 * 12; idx += 256) {
        int rr = idx / 12, seg = idx - rr * 12;
        int lg = t0 - 3 + rr;
        bf16x8 v;
        if (lg >= 0) {
            const unsigned short* src = zxb + (size_t)(b * L_ + lg) * DIP +
                                        (seg < 8 ? (DI + h * HD + seg * 8) : (1024 + (seg - 8) * 8));
            v = *(const bf16x8*)src;
        } else {
#pragma unroll
            for (int j = 0; j < 8; j++) v[j] = 0;
        }
        int col = (seg < 8) ? seg * 8 : (64 + (seg - 8) * 8);
        *(bf16x8*)&Zl[rr * 96 + col] = v;
    }
    // ---- zero-fill Cbf/Bbf K-pad ----
    {
        bf16x8 z8;
#pragma unroll
        for (int j = 0; j < 8; j++) z8[j] = 0;
        *(bf16x8*)&Cbf[tid * 8] = z8;
        *(bf16x8*)&Bbf[tid * 8] = z8;
    }
    // ---- dt / ldA / log-cumsum ----
    if (tid < 64) {
        float raw = dtraw[(size_t)(b * L_ + t0 + tid) * NH + h] + dtb[h];
        float dtv = (raw > 20.f) ? raw : log1pf(__expf(raw));
        float v = -__expf(Alog[h]) * dtv;
#pragma unroll
        for (int off = 1; off < 64; off <<= 1) {
            float u = __shfl_up(v, off);
            if (tid >= off) v += u;
        }
        dts[tid] = dtv;
        Lc[tid] = v;
        float lend = __shfl(v, 63);
        coefS[tid] = __expf(lend - v) * dtv;
        cumLg[(size_t)(bh * NC + c) * Q_ + tid] = v;
        if (tid == 63) Pg[bh * NC + c] = __expf(v);
    }
    __syncthreads();

    // ---- X-conv (phase-2 mapping): 16 vals/thread, fp32 regs + bf16 Xt ----
    float xreg[4][4];
#pragma unroll
    for (int pt = 0; pt < 4; pt++) {
#pragma unroll
        for (int r = 0; r < 4; r++) {
            int t = w * 16 + kq * 4 + r;
            int p = pt * 16 + lr;
            int cc = h * HD + p;
            float acc = cb[cc];
#pragma unroll
            for (int k = 0; k < 4; k++)
                acc = fmaf(bf2f(Zl[(t + k) * 96 + p]), cw[cc * 4 + k], acc);
            float s = acc * fast_sig(acc);
            xreg[pt][r] = s;
            Xt[p * 72 + t] = f2bf(s);
        }
    }
    // ---- B/C conv ----
    for (int idx = tid; idx < Q_ * 32; idx += 256) {
        int t = idx >> 5, n32 = idx & 31;
        int cc = DI + n32;
        float acc = cb[cc];
#pragma unroll
        for (int k = 0; k < 4; k++)
            acc = fmaf(bf2f(Zl[(t + k) * 96 + 64 + n32]), cw[cc * 4 + k], acc);
        float s = acc * fast_sig(acc);
        if (n32 < 16) {
            int n = n32;
            Bbf[t * 32 + (((n >> 3) ^ (t & 3)) * 8) + (n & 7)] = f2bf(dts[t] * s);
            Btw[n * 72 + t] = f2bf(coefS[t] * s);
        } else {
            int n = n32 - 16;
            Cbf[t * 32 + (((n >> 3) ^ (t & 3)) * 8) + (n & 7)] = f2bf(s);
            if (h == 0) Cc[((size_t)(b * L_ + t0 + t)) * DSZ + n] = s;
        }
    }
    __syncthreads();

    f32x4 zero = {0.f, 0.f, 0.f, 0.f};

    // phase 1: CB tiles
    f32x4 cbt[4];
    {
        bf16x8 af = *(const bf16x8*)&Cbf[(w * 16 + lr) * 32 + ((kq ^ (lr & 3)) * 8)];
#pragma unroll
        for (int st = 0; st < 4; st++) {
            bf16x8 bf = *(const bf16x8*)&Bbf[(st * 16 + lr) * 32 + ((kq ^ (lr & 3)) * 8)];
            cbt[st] = __builtin_amdgcn_mfma_f32_16x16x32_bf16(af, bf, zero, 0, 0, 0);
        }
    }
    // mask + decay -> Mbf
#pragma unroll
    for (int st = 0; st < 4; st++) {
#pragma unroll
        for (int r = 0; r < 4; r++) {
            int t = w * 16 + kq * 4 + r;
            int s = st * 16 + lr;
            float m = (s <= t) ? __expf(Lc[t] - Lc[s]) * cbt[st][r] : 0.f;
            Mbf[t * 64 + (((s >> 3) ^ (t & 7)) * 8) + (s & 7)] = f2bf(m);
        }
    }
    __syncthreads();

    // phase 2: Y = M*X + D*x -> bf16 ybuf
    {
        unsigned short* base_y = ybuf + ((size_t)b * L_ + t0) * DI + h * HD;
        f32x4 acc[4];
#pragma unroll
        for (int pt = 0; pt < 4; pt++) acc[pt] = zero;
#pragma unroll
        for (int ks = 0; ks < 2; ks++) {
            bf16x8 af = *(const bf16x8*)&Mbf[(w * 16 + lr) * 64 + (((ks * 4 + kq) ^ (lr & 7)) * 8)];
#pragma unroll
            for (int pt = 0; pt < 4; pt++) {
                bf16x8 bf = *(const bf16x8*)&Xt[(pt * 16 + lr) * 72 + ks * 32 + kq * 8];
                acc[pt] = __builtin_amdgcn_mfma_f32_16x16x32_bf16(af, bf, acc[pt], 0, 0, 0);
            }
        }
#pragma unroll
        for (int pt = 0; pt < 4; pt++) {
#pragma unroll
            for (int r = 0; r < 4; r++) {
                int t = w * 16 + kq * 4 + r;
                int p = pt * 16 + lr;
                base_y[(size_t)t * DI + p] = f2bf(acc[pt][r] + Dval * xreg[pt][r]);
            }
        }
    }

    // phase 3: chunk state S = X^T * (coef*B)
    {
        f32x4 sacc = zero;
#pragma unroll
        for (int ks = 0; ks < 2; ks++) {
            bf16x8 af = *(const bf16x8*)&Xt[(w * 16 + lr) * 72 + ks * 32 + kq * 8];
            bf16x8 bf = *(const bf16x8*)&Btw[lr * 72 + ks * 32 + kq * 8];
            sacc = __builtin_amdgcn_mfma_f32_16x16x32_bf16(af, bf, sacc, 0, 0, 0);
        }
#pragma unroll
        for (int r = 0; r < 4; r++) {
            int p = w * 16 + kq * 4 + r;
            Sg[((size_t)(bh * NC + c) * HD + p) * DSZ + lr] = sacc[r];
        }
    }
}

// ---------------- chunked scan stage 2 ----------------
__global__ __launch_bounds__(256) void k_scan2(const float* __restrict__ Sg, const float* __restrict__ Pg,
                                               float* __restrict__ Hg) {
    int bh = blockIdx.x;
    int tid = threadIdx.x;
    int p = tid >> 2, n0 = (tid & 3) * 4;
    float4 H = make_float4(0.f, 0.f, 0.f, 0.f);
    for (int c = 0; c < NC; c++) {
        size_t base = ((size_t)(bh * NC + c) * HD + p) * DSZ + n0;
        float P = Pg[bh * NC + c];
        float4 S = *(const float4*)(Sg + base);
        *(float4*)(Hg + base) = H;
        H.x = fmaf(P, H.x, S.x);
        H.y = fmaf(P, H.y, S.y);
        H.z = fmaf(P, H.z, S.z);
        H.w = fmaf(P, H.w, S.w);
    }
}

// ---------------- fused scan stage 3 + gated RMSNorm -> bf16 yn ----------------
__global__ __launch_bounds__(256) void k_scan3g(const unsigned short* __restrict__ ybuf,
                                                const unsigned short* __restrict__ zxb,
                                                const float* __restrict__ Hg, const float* __restrict__ cumLg,
                                                const float* __restrict__ Cc, const float* __restrict__ nw,
                                                unsigned short* __restrict__ yn_bf) {
    int b = blockIdx.x, by = blockIdx.y;
    int c64 = by >> 2, tl0 = (by & 3) * 16;
    int t0 = by * 16;
    int tid = threadIdx.x;
    __shared__ float Hsn[DSZ * 576];   // n*576 + p*9 + hh  (36 KB)
    __shared__ float Lq[NH][16];

    {
        int p = tid & 63, hp = tid >> 6;
#pragma unroll
        for (int ho = 0; ho < 2; ho++) {
            int hh = hp * 2 + ho;
            const float* src = Hg + (((size_t)(b * NH + hh) * NC + c64) * HD + p) * DSZ;
            float* dst = &Hsn[p * 9 + hh];
#pragma unroll
            for (int nq = 0; nq < 4; nq++) {
                float4 v = *(const float4*)(src + nq * 4);
                dst[(nq * 4 + 0) * 576] = v.x;
                dst[(nq * 4 + 1) * 576] = v.y;
                dst[(nq * 4 + 2) * 576] = v.z;
                dst[(nq * 4 + 3) * 576] = v.w;
            }
        }
    }
    if (tid < 128) {
        int hh = tid >> 4, t = tid & 15;
        Lq[hh][t] = cumLg[((size_t)(b * NH + hh) * NC + c64) * Q_ + tl0 + t];
    }
    __syncthreads();

    int t = tid >> 4, q = tid & 15;
    int hh = q >> 1, p0 = (q & 1) * 32;
    size_t bl = (size_t)b * L_ + t0 + t;
    float ef = __expf(Lq[hh][t]);

    float Cr[16];
#pragma unroll
    for (int k = 0; k < 4; k++) {
        float4 v = *(const float4*)(Cc + bl * DSZ + k * 4);
        Cr[4 * k + 0] = ef * v.x;
        Cr[4 * k + 1] = ef * v.y;
        Cr[4 * k + 2] = ef * v.z;
        Cr[4 * k + 3] = ef * v.w;
    }

    const unsigned short* yrow = ybuf + bl * DI + hh * HD + p0;
    const unsigned short* zrow = zxb + bl * DIP + hh * HD + p0;
    unsigned short yv[32], zv[32];
#pragma unroll
    for (int k = 0; k < 4; k++) *(bf16x8*)&yv[k * 8] = *(const bf16x8*)(yrow + k * 8);
#pragma unroll
    for (int k = 0; k < 4; k++) *(bf16x8*)&zv[k * 8] = *(const bf16x8*)(zrow + k * 8);

    float yg[32];
    float ss = 0.f;
#pragma unroll
    for (int j = 0; j < 32; j++) {
        const float* hp_ = &Hsn[(p0 + j) * 9 + hh];
        float d = 0.f;
#pragma unroll
        for (int n = 0; n < DSZ; n++) d = fmaf(Cr[n], hp_[n * 576], d);
        float y = bf2f(yv[j]) + d;
        float z = bf2f(zv[j]);
        yg[j] = y * z * fast_sig(z);
        ss = fmaf(yg[j], yg[j], ss);
    }
    ss += __shfl_xor(ss, 1);
    ss += __shfl_xor(ss, 2);
    ss += __shfl_xor(ss, 4);
    ss += __shfl_xor(ss, 8);
    float r = rsqrtf(ss * (1.f / DI) + 1e-5f);

    const float* nwp = nw + hh * HD + p0;
    unsigned short* dst = yn_bf + bl * DI + hh * HD + p0;
#pragma unroll
    for (int k = 0; k < 4; k++) {
        bf16x8 o;
#pragma unroll
        for (int j = 0; j < 8; j++) o[j] = (short)f2bf(yg[k * 8 + j] * r * nwp[k * 8 + j]);
        *(bf16x8*)(dst + k * 8) = o;
    }
}

// ---------------- residual add + LayerNorm + mask (wave-per-row, no barriers) ----------------
__global__ __launch_bounds__(256) void k_ln(const unsigned short* __restrict__ tmp, float* __restrict__ h,
                                            unsigned short* __restrict__ h_bf,
                                            const float* __restrict__ lnw, const float* __restrict__ lnb,
                                            const float* __restrict__ mask) {
    int row = blockIdx.x * 4 + (threadIdx.x >> 6);
    int lane = threadIdx.x & 63;
    size_t base = (size_t)row * DM + lane * 4;
    ushort4 tv = *(const ushort4*)(tmp + base);
    float4 hv = *(const float4*)(h + base);
    float v[4] = {bf2f(tv.x) + hv.x, bf2f(tv.y) + hv.y, bf2f(tv.z) + hv.z, bf2f(tv.w) + hv.w};
    float s = v[0] + v[1] + v[2] + v[3];
#pragma unroll
    for (int m = 1; m < 64; m <<= 1) s += __shfl_xor(s, m);
    float mu = s * (1.f / DM);
    float q = 0.f;
#pragma unroll
    for (int j = 0; j < 4; j++) {
        float d = v[j] - mu;
        q = fmaf(d, d, q);
    }
#pragma unroll
    for (int m = 1; m < 64; m <<= 1) q += __shfl_xor(q, m);
    float rs = rsqrtf(q * (1.f / DM) + 1e-5f);
    float mk = mask[row];
    float4 wv = *(const float4*)(lnw + lane * 4);
    float4 bv = *(const float4*)(lnb + lane * 4);
    float o[4];
    o[0] = ((v[0] - mu) * rs * wv.x + bv.x) * mk;
    o[1] = ((v[1] - mu) * rs * wv.y + bv.y) * mk;
    o[2] = ((v[2] - mu) * rs * wv.z + bv.z) * mk;
    o[3] = ((v[3] - mu) * rs * wv.w + bv.w) * mk;
    *(float4*)(h + base) = make_float4(o[0], o[1], o[2], o[3]);
    ushort4 ob;
    ob.x = f2bf(o[0]); ob.y = f2bf(o[1]); ob.z = f2bf(o[2]); ob.w = f2bf(o[3]);
    *(ushort4*)(h_bf + base) = ob;
}

// ---------------- 2-stage mean-pool + classifier ----------------
__global__ __launch_bounds__(256) void k_pool1(const float* __restrict__ h, float* __restrict__ part) {
    int b = blockIdx.x, g = blockIdx.y, d = threadIdx.x;
    const float* hb = h + ((size_t)b * L_ + g * 128) * DM + d;
    float s = 0.f;
    for (int l = 0; l < 128; l++) s += hb[(size_t)l * DM];
    part[((size_t)b * 16 + g) * DM + d] = s;
}

__global__ __launch_bounds__(256) void k_pool2(const float* __restrict__ part, const float* __restrict__ cw,
                                               const float* __restrict__ cb, float* __restrict__ out) {
    int b = blockIdx.x, tid = threadIdx.x;
    float s = 0.f;
#pragma unroll
    for (int g = 0; g < 16; g++) s += part[((size_t)b * 16 + g) * DM + tid];
    s *= (1.0f / L_);
    float p0 = s * cw[tid];
    float p1 = s * cw[DM + tid];
#pragma unroll
    for (int m = 1; m < 64; m <<= 1) {
        p0 += __shfl_xor(p0, m);
        p1 += __shfl_xor(p1, m);
    }
    __shared__ float r0[4], r1[4];
    if ((tid & 63) == 0) { r0[tid >> 6] = p0; r1[tid >> 6] = p1; }
    __syncthreads();
    if (tid == 0) {
        out[b * 2 + 0] = r0[0] + r0[1] + r0[2] + r0[3] + cb[0];
        out[b * 2 + 1] = r1[0] + r1[1] + r1[2] + r1[3] + cb[1];
    }
}

extern "C" void kernel_launch(void* const* d_in, const int* in_sizes, int n_in,
                              void* d_out, int out_size, void* d_ws, size_t ws_size,
                              hipStream_t stream) {
    const int*   x    = (const int*)d_in[0];
    const float* mask = (const float*)d_in[1];
    const float* emb  = (const float*)d_in[2];
    const float* pos  = (const float*)d_in[3];
    const float* Wi   = (const float*)d_in[4];
    const float* cw   = (const float*)d_in[5];
    const float* cb   = (const float*)d_in[6];
    const float* dtb  = (const float*)d_in[7];
    const float* Alog = (const float*)d_in[8];
    const float* Dp   = (const float*)d_in[9];
    const float* nw   = (const float*)d_in[10];
    const float* Wo   = (const float*)d_in[11];
    const float* lnw  = (const float*)d_in[12];
    const float* lnb  = (const float*)d_in[13];
    const float* clsw = (const float*)d_in[14];
    const float* clsb = (const float*)d_in[15];
    float* out = (float*)d_out;

    float* ws    = (float*)d_ws;
    float* h     = ws;                                   // 16384 x 256 fp32
    float* dtraw = h + (size_t)B_ * L_ * DM;             // 16384 x 8
    float* Sg    = dtraw + (size_t)B_ * L_ * NH;         // 8.4 MB
    float* Pg    = Sg + (size_t)64 * NC * HD * DSZ;      // 2048
    float* cumL  = Pg + (size_t)64 * NC;                 // 64*32*64
    float* Hg    = cumL + (size_t)64 * NC * Q_;          // 8.4 MB
    float* Cc    = Hg + (size_t)64 * NC * HD * DSZ;      // 16384 x 16
    float* pool  = Cc + (size_t)B_ * L_ * DSZ;           // 8*16*256
    unsigned short* zxb   = (unsigned short*)(pool + (size_t)B_ * 16 * DM);  // 16384 x 1064 bf16
    unsigned short* ybuf  = zxb + (size_t)B_ * L_ * DIP;                     // 16384 x 512 bf16
    unsigned short* tmp   = ybuf + (size_t)B_ * L_ * DI;                     // 16384 x 256 bf16
    unsigned short* h_bf  = tmp + (size_t)B_ * L_ * DM;
    unsigned short* yn_bf = h_bf + (size_t)B_ * L_ * DM;
    unsigned short* Wi_bf = yn_bf + (size_t)B_ * L_ * DI;
    unsigned short* Wo_bf = Wi_bf + (size_t)4 * DIP * DM;

    k_f2bf<<<(4 * DIP * DM / 4 + 255) / 256, 256, 0, stream>>>(Wi, Wi_bf, 4 * DIP * DM / 4);
    k_f2bf<<<(4 * DM * DI / 4 + 255) / 256, 256, 0, stream>>>(Wo, Wo_bf, 4 * DM * DI / 4);

    k_embed<<<(B_ * L_ * DM + 255) / 256, 256, 0, stream>>>(x, mask, emb, pos, h, h_bf);

    for (int i = 0; i < 4; i++) {
        // zxbcdt = h @ Wi^T -> bf16 zxb (+ fp32 dtraw cols)
        k_gemm<1><<<dim3(B_ * L_ / 128, (DIP + 127) / 128), 256, 0, stream>>>(
            h_bf, DM, Wi_bf + (size_t)i * DIP * DM, DM, DIP, zxb, DIP, DM, dtraw);
        // fused conv+silu+dt + intra-chunk scan (MFMA) -> bf16 ybuf
        k_scan1c<<<dim3(64, NC), 256, 0, stream>>>(
            zxb, dtraw, cw + (size_t)i * CD * 4, cb + i * CD, dtb + i * NH, Alog + i * NH,
            Dp + i * NH, ybuf, Sg, Pg, cumL, Cc);
        k_scan2<<<64, 256, 0, stream>>>(Sg, Pg, Hg);
        // fused cross-chunk + gated RMSNorm -> bf16 yn
        k_scan3g<<<dim3(B_, 128), 256, 0, stream>>>(ybuf, zxb, Hg, cumL, Cc, nw + (size_t)i * DI, yn_bf);
        // out = yn @ Wo^T -> bf16 tmp
        k_gemm<2><<<dim3(B_ * L_ / 128, DM / 128), 256, 0, stream>>>(
            yn_bf, DI, Wo_bf + (size_t)i * DM * DI, DI, DM, tmp, DM, DI, nullptr);
        k_ln<<<B_ * L_ / 4, 256, 0, stream>>>(tmp, h, h_bf, lnw, lnb, mask);
    }

    k_pool1<<<dim3(B_, 16), 256, 0, stream>>>(h, pool);
    k_pool2<<<B_, 256, 0, stream>>>(pool, clsw, clsb, out);
}